// Round 11
// baseline (145.278 us; speedup 1.0000x reference)
//
#include <hip/hip_runtime.h>
#include <stdint.h>

typedef __bf16  bf16x8 __attribute__((ext_vector_type(8)));
typedef float   f32x4  __attribute__((ext_vector_type(4)));

#define MFMA16(a, b, c) __builtin_amdgcn_mfma_f32_16x16x32_bf16((a), (b), (c), 0, 0, 0)

__device__ __forceinline__ float bf2f(unsigned short u) {
    union { unsigned u; float f; } v; v.u = ((unsigned)u) << 16; return v.f;
}
__device__ __forceinline__ unsigned short f2bf(float f) {
    union { float f; unsigned u; } v; v.f = f;
    unsigned r = v.u + 0x7fffu + ((v.u >> 16) & 1u);
    return (unsigned short)(r >> 16);
}
// native HW convert (v_cvt, RNE)
__device__ __forceinline__ unsigned short f2bf_hw(float f) {
    union { __bf16 h; unsigned short u; } v; v.h = (__bf16)f; return v.u;
}

// async global->LDS, 16B per lane. LDS dest is wave-uniform base + lane*16 (linear).
__device__ __forceinline__ void gload16(const unsigned short* g, unsigned short* l) {
    __builtin_amdgcn_global_load_lds(
        (const __attribute__((address_space(1))) unsigned int*)g,
        (__attribute__((address_space(3))) unsigned int*)l,
        16, 0, 0);
}

// B=4, T=1024, D=512, H=8, DH=64, MAX_REL=256. Inputs fp32 dict-order; OUTPUT FP32.
// R28: attn split-K over keys (z=2, grid 1024 -> 3 blocks/CU vs 2). Valid because
// softmax max m comes from the R window only (key-independent) => partials add.
// Partial f32 acco+lsum to ws; new attn_combine normalizes into Qb. Rest = R27
// (136.8us known-good: Q pre-scaled, f2bf_hw, qkv gload_lds+XOR staging).

// ---------- 1. prep: cast W,x fp32->bf16 AND x column-sum partials ----------
__global__ __launch_bounds__(256) void prep_kernel(const float* __restrict__ Wq,
                                                   const float* __restrict__ Wk,
                                                   const float* __restrict__ Wv,
                                                   const float* __restrict__ Wo,
                                                   const float* __restrict__ x,
                                                   unsigned short* __restrict__ Wbf,
                                                   unsigned short* __restrict__ xbf,
                                                   float* __restrict__ part) {
    int bid = blockIdx.x;
    if (bid < 1024) {             // weights: 262144 chunks of 4
        int idx = bid * 256 + threadIdx.x;
        int which = idx >> 16, off = (idx & 65535) << 2;
        const float* src = which == 0 ? Wq : which == 1 ? Wk : which == 2 ? Wv : Wo;
        f32x4 v = *(const f32x4*)(src + off);
        ushort4 r;
        r.x = f2bf(v[0]); r.y = f2bf(v[1]); r.z = f2bf(v[2]); r.w = f2bf(v[3]);
        *(ushort4*)(Wbf + (size_t)which * 262144 + off) = r;
    } else if (bid < 3072) {      // x: 524288 chunks of 4
        int cidx = (bid - 1024) * 256 + threadIdx.x;
        size_t off = (size_t)cidx << 2;
        f32x4 v = *(const f32x4*)(x + off);
        ushort4 r;
        r.x = f2bf(v[0]); r.y = f2bf(v[1]); r.z = f2bf(v[2]); r.w = f2bf(v[3]);
        *(ushort4*)(xbf + off) = r;
    } else {                      // xsum partials: 128 blocks = (4 b) x (32 chunks)
        int t = bid - 3072;
        int b = t >> 5, chunk = t & 31, k = threadIdx.x;
        const float* p = x + (size_t)b * 1024 * 512 + (size_t)chunk * 32 * 512;
        float s0 = 0.f, s1 = 0.f;
        for (int tt = 0; tt < 32; ++tt) {
            s0 += p[tt * 512 + k];
            s1 += p[tt * 512 + k + 256];
        }
        part[(size_t)(b * 32 + chunk) * 512 + k]       = s0;
        part[(size_t)(b * 32 + chunk) * 512 + k + 256] = s1;
    }
}

// ---------- 2. qkvq: FUSED QKV projection (y<64) + qsum reduction (y>=64) ----------
// Q written pre-scaled by 0.125*log2e (softmax fold); K/V unscaled.
__global__ __launch_bounds__(256) void qkvq_fused(
    const unsigned short* __restrict__ xbf, const unsigned short* __restrict__ Wbf,
    const float* __restrict__ bq, const float* __restrict__ bk, const float* __restrict__ bv,
    unsigned short* __restrict__ Qb, unsigned short* __restrict__ Kb,
    unsigned short* __restrict__ VbT,
    const float* __restrict__ part, const float* __restrict__ Wq,
    float* __restrict__ Qsum) {

    __shared__ __align__(16) unsigned short Tl[2][4][4096];   // [buf][tensor][64x64]

    int tid = threadIdx.x;

    if (blockIdx.y >= 64) {
        // ---- qsum role: 512 blocks; reuse Tl as float scratch ----
        float* xs = (float*)&Tl[0][0][0];
        int bid = (blockIdx.y - 64) * 8 + blockIdx.x;     // 0..511
        int b = bid >> 7, wave = tid >> 6, lane = tid & 63;
        int n = (bid & 127) * 4 + wave;
        for (int k = tid; k < 512; k += 256) {
            float s = 0.f;
            for (int c = 0; c < 32; ++c) s += part[(size_t)(b * 32 + c) * 512 + k];
            xs[k] = s;
        }
        __syncthreads();
        const float* w = Wq + (size_t)n * 512;
        float s = 0.f;
        for (int j = lane; j < 512; j += 64) s += xs[j] * w[j];
        for (int off = 32; off; off >>= 1) s += __shfl_xor(s, off, 64);
        if (lane == 0) Qsum[b * 512 + n] = s + 1024.0f * bq[n];
        return;
    }

    // ---- qkv role ----
    const int m0 = blockIdx.y * 64;
    const int n0 = blockIdx.x * 64;

    int wave = tid >> 6, lane = tid & 63, quad = lane >> 4, l16 = lane & 15;
    const int wr = (wave >> 1) * 32, wc = (wave & 1) * 32;   // 2x2 wave tiling

    // wave w stages tensor w: 0 = x-tile, 1..3 = Wq/Wk/Wv-tile
    const unsigned short* gbase = (wave == 0)
        ? xbf + (size_t)m0 * 512
        : Wbf + (size_t)(wave - 1) * 262144 + (size_t)n0 * 512;
    const int srow = lane >> 3;      // row within 8-row segment
    const int schunk = lane & 7;     // 16B chunk within row

    f32x4 acc[3][2][2] = {};

    // prologue: stage k0=0 into buffer 0
    {
        unsigned short* lb = &Tl[0][wave][0];
#pragma unroll
        for (int seg = 0; seg < 8; ++seg) {
            int row = seg * 8 + srow;
            int chunk = schunk ^ (row & 7);                 // inverse-swizzled source
            gload16(gbase + (size_t)row * 512 + chunk * 8, lb + seg * 512);
        }
    }

    int p = 0;
    for (int k0 = 0; k0 < 512; k0 += 64) {
        __syncthreads();             // buffer p landed (compiler drains vmcnt here)
        int kn = k0 + 64;
        if (kn < 512) {              // async-stage next tile; hidden under MFMAs below
            unsigned short* lb = &Tl[p ^ 1][wave][0];
#pragma unroll
            for (int seg = 0; seg < 8; ++seg) {
                int row = seg * 8 + srow;
                int chunk = schunk ^ (row & 7);
                gload16(gbase + (size_t)row * 512 + kn + chunk * 8, lb + seg * 512);
            }
        }
#pragma unroll
        for (int kk = 0; kk < 2; ++kk) {
            // read-side XOR: (wr|wc are multiples of 16 so row&7 == l16&7)
            int chk = (((kk * 4 + quad) ^ (l16 & 7)) << 3);
            bf16x8 af0 = *(const bf16x8*)(&Tl[p][0][(wr + l16) * 64 + chk]);
            bf16x8 af1 = *(const bf16x8*)(&Tl[p][0][(wr + 16 + l16) * 64 + chk]);
#pragma unroll
            for (int w = 0; w < 3; ++w) {
                bf16x8 b0 = *(const bf16x8*)(&Tl[p][1 + w][(wc + l16) * 64 + chk]);
                bf16x8 b1 = *(const bf16x8*)(&Tl[p][1 + w][(wc + 16 + l16) * 64 + chk]);
                acc[w][0][0] = MFMA16(af0, b0, acc[w][0][0]);
                acc[w][0][1] = MFMA16(af0, b1, acc[w][0][1]);
                acc[w][1][0] = MFMA16(af1, b0, acc[w][1][0]);
                acc[w][1][1] = MFMA16(af1, b1, acc[w][1][1]);
            }
        }
        p ^= 1;
    }

    // Q, K epilogue (C: row = m0+wr+mi*16+quad*4+reg, col = n0+wc+ni*16+l16)
    // Q pre-scaled by 0.125*log2e so attn's softmax drops the per-element mul.
    for (int w = 0; w < 2; ++w) {
        unsigned short* Out = (w == 0) ? Qb : Kb;
        const float* bias = (w == 0) ? bq : bk;
        const float scl = (w == 0) ? 0.18033688f : 1.0f;
        for (int ni = 0; ni < 2; ++ni) {
            int col = n0 + wc + ni * 16 + l16;
            int h = col >> 6, d = col & 63;
            float bv_ = bias[col];
            for (int mi = 0; mi < 2; ++mi)
                for (int reg = 0; reg < 4; ++reg) {
                    int row = m0 + wr + mi * 16 + quad * 4 + reg;   // = b*1024 + t
                    int b = row >> 10, t = row & 1023;
                    Out[(((size_t)(b * 8 + h) * 1024 + t) << 6) + d] =
                        f2bf((acc[w][mi][ni][reg] + bv_) * scl);
                }
        }
    }
    // V epilogue: transpose via LDS (reuse Tl[0], stride 72 => 144B rows, 16B-aligned)
    __syncthreads();
    unsigned short* Vt = &Tl[0][0][0];                     // [64][72]
    for (int ni = 0; ni < 2; ++ni) {
        int dl = wc + ni * 16 + l16;
        float bv_ = bv[n0 + dl];
        for (int mi = 0; mi < 2; ++mi)
            for (int reg = 0; reg < 4; ++reg)
                Vt[dl * 72 + wr + mi * 16 + quad * 4 + reg] = f2bf(acc[2][mi][ni][reg] + bv_);
    }
    __syncthreads();
    const int h = n0 >> 6, b = m0 >> 10, tg = m0 & 1023;
    for (int c = tid; c < 512; c += 256) {
        int dl = c >> 3, seg = (c & 7) << 3;
        *(uint4*)(VbT + (((size_t)((b * 8 + h) * 64 + dl)) << 10) + tg + seg) =
            *(const uint4*)(&Vt[dl * 72 + seg]);
    }
}

// ---------- 3. R bias (wave per output; 4104 blocks). Writes R * 0.125 * log2e ----------
__global__ __launch_bounds__(256) void rbias_kernel(const float* __restrict__ Qsum,
                                                    const float* __restrict__ relT,
                                                    float* __restrict__ R) {
    int idx = blockIdx.x * 4 + (threadIdx.x >> 6);
    if (idx >= 4 * 8 * 513) return;
    int lane = threadIdx.x & 63;
    int delta = idx % 513, bh = idx / 513;
    int b = bh >> 3, h = bh & 7;
    float s = Qsum[b * 512 + h * 64 + lane] * relT[(size_t)delta * 64 + lane];
    for (int off = 32; off; off >>= 1) s += __shfl_xor(s, off, 64);
    if (lane == 0) R[idx] = 0.18033688f * s;    // 0.125 * log2(e)
}

// ---------- 4. MFMA flash attention, tile-64, split-K z=2, partial outputs ----------
// Q pre-scaled; R pre-scaled; m from R window (key-independent) => partials add.
__global__ __launch_bounds__(256) void attn_kernel(
    const unsigned short* __restrict__ Qb,
    const unsigned short* __restrict__ Kb, const unsigned short* __restrict__ VbT,
    const float* __restrict__ R,
    float* __restrict__ accoP, float* __restrict__ lsumP) {
    const int bh = blockIdx.y;
    const int t0 = blockIdx.x * 64;
    const int sbase = blockIdx.z << 9;            // 0 or 512
    __shared__ __align__(16) unsigned short Ks[2][64][72];
    __shared__ __align__(16) unsigned short Vt[2][64][72];
    __shared__ __align__(16) unsigned short Ps[64][72];
    __shared__ float Rs[513];
    __shared__ float Ms[64];

    int tid = threadIdx.x, wave = tid >> 6, lane = tid & 63, quad = lane >> 4, l16 = lane & 15;

    for (int i = tid; i < 513; i += 256) Rs[i] = R[bh * 513 + i];

    const unsigned short* Qp = Qb + ((size_t)bh * 1024 + t0) * 64;
    int arow = wave * 16 + l16;
    bf16x8 qf0 = *(const bf16x8*)(Qp + arow * 64 + quad * 8);
    bf16x8 qf1 = *(const bf16x8*)(Qp + arow * 64 + 32 + quad * 8);

    const unsigned short* Kp  = Kb  + (size_t)bh * 65536;
    const unsigned short* Vtp = VbT + (size_t)bh * 65536;

    int c0 = tid, c1 = tid + 256;
    int r0 = c0 >> 3, kc0 = (c0 & 7) << 3;
    int r1 = c1 >> 3, kc1 = (c1 & 7) << 3;

    uint4 kreg0 = *(const uint4*)(Kp + (size_t)(sbase + r0) * 64 + kc0);
    uint4 kreg1 = *(const uint4*)(Kp + (size_t)(sbase + r1) * 64 + kc1);
    uint4 vreg0 = *(const uint4*)(Vtp + ((size_t)r0 << 10) + sbase + kc0);
    uint4 vreg1 = *(const uint4*)(Vtp + ((size_t)r1 << 10) + sbase + kc1);

    // ---- folded rmax: window max over staged Rs; 4 scanner threads per row ----
    __syncthreads();                      // Rs complete
    {
        int r = tid >> 2, q = tid & 3;    // 64 rows x 4 scanners (adjacent lanes)
        int t = t0 + r;
        int lo = 256 - (t < 256 ? t : 256);
        int hi = 256 + ((1023 - t) < 256 ? (1023 - t) : 256);
        float m = -3.4e38f;
        for (int j = lo + q; j <= hi; j += 4) m = fmaxf(m, Rs[j]);
        m = fmaxf(m, __shfl_xor(m, 1, 64));
        m = fmaxf(m, __shfl_xor(m, 2, 64));
        if (q == 0) Ms[r] = m;
    }
    __syncthreads();                      // Ms complete
    float mrow[4];
    for (int reg = 0; reg < 4; ++reg)
        mrow[reg] = Ms[wave * 16 + quad * 4 + reg];

    f32x4 acco[4] = {};
    float lsum[4] = {0.f, 0.f, 0.f, 0.f};
    int p = 0;

    for (int s0 = sbase; s0 < sbase + 512; s0 += 64) {
        *(uint4*)(&Ks[p][r0][kc0]) = kreg0;
        *(uint4*)(&Ks[p][r1][kc1]) = kreg1;
        *(uint4*)(&Vt[p][r0][kc0]) = vreg0;
        *(uint4*)(&Vt[p][r1][kc1]) = vreg1;
        int sn = s0 + 64;
        if (sn < sbase + 512) {
            kreg0 = *(const uint4*)(Kp + (size_t)(sn + r0) * 64 + kc0);
            kreg1 = *(const uint4*)(Kp + (size_t)(sn + r1) * 64 + kc1);
            vreg0 = *(const uint4*)(Vtp + ((size_t)r0 << 10) + sn + kc0);
            vreg1 = *(const uint4*)(Vtp + ((size_t)r1 << 10) + sn + kc1);
        }
        __syncthreads();

        f32x4 accs[4] = {};
        for (int nt = 0; nt < 4; ++nt) {
            bf16x8 kf0 = *(const bf16x8*)(&Ks[p][nt * 16 + l16][quad * 8]);
            accs[nt] = MFMA16(qf0, kf0, accs[nt]);
            bf16x8 kf1 = *(const bf16x8*)(&Ks[p][nt * 16 + l16][32 + quad * 8]);
            accs[nt] = MFMA16(qf1, kf1, accs[nt]);
        }

        for (int reg = 0; reg < 4; ++reg) {
            int tt = t0 + wave * 16 + quad * 4 + reg;
            for (int nt = 0; nt < 4; ++nt) {
                int ss = s0 + nt * 16 + l16;
                int dlt = ss - tt;
                dlt = dlt > 256 ? 256 : (dlt < -256 ? -256 : dlt);
                // Q pre-scaled: score already in base-2 units
                float v = accs[nt][reg] + Rs[dlt + 256];
                float p_ = __builtin_amdgcn_exp2f(v - mrow[reg]);
                lsum[reg] += p_;
                Ps[wave * 16 + quad * 4 + reg][nt * 16 + l16] = f2bf_hw(p_);
            }
        }

        for (int kk = 0; kk < 2; ++kk) {
            bf16x8 pf = *(const bf16x8*)(&Ps[wave * 16 + l16][kk * 32 + quad * 8]);
            for (int nt = 0; nt < 4; ++nt) {
                bf16x8 vf = *(const bf16x8*)(&Vt[p][nt * 16 + l16][kk * 32 + quad * 8]);
                acco[nt] = MFMA16(pf, vf, acco[nt]);
            }
        }
        p ^= 1;
    }

    for (int reg = 0; reg < 4; ++reg)
        for (int off = 1; off < 16; off <<= 1) lsum[reg] += __shfl_xor(lsum[reg], off, 64);

    // partial outputs (no normalization here)
    float* aP = accoP + (size_t)blockIdx.z * (32768ull * 64);
    float* lP = lsumP + blockIdx.z * 32768;
    if (l16 == 0)
        for (int reg = 0; reg < 4; ++reg)
            lP[bh * 1024 + t0 + wave * 16 + quad * 4 + reg] = lsum[reg];
    for (int nt = 0; nt < 4; ++nt)
        for (int reg = 0; reg < 4; ++reg) {
            int tt = t0 + wave * 16 + quad * 4 + reg;
            aP[((size_t)bh * 1024 + tt) * 64 + nt * 16 + l16] = acco[nt][reg];
        }
}

// ---------- 4b. combine: Qb = (a0+a1) / (l0+l1), bf16 ----------
__global__ __launch_bounds__(256) void attn_combine(const float* __restrict__ accoP,
                                                    const float* __restrict__ lsumP,
                                                    unsigned short* __restrict__ Qb) {
    int c = blockIdx.x * 256 + threadIdx.x;      // 262144 chunks of 8 floats
    int rr = c >> 3, d0 = (c & 7) << 3;
    const float* a0 = accoP + (size_t)rr * 64 + d0;
    const float* a1 = a0 + 32768ull * 64;
    float rinv = 1.0f / (lsumP[rr] + lsumP[32768 + rr]);
    f32x4 v0a = *(const f32x4*)a0,       v1a = *(const f32x4*)a1;
    f32x4 v0b = *(const f32x4*)(a0 + 4), v1b = *(const f32x4*)(a1 + 4);
    union { unsigned short u[8]; uint4 v; } r;
    for (int i = 0; i < 4; ++i) {
        r.u[i]     = f2bf_hw((v0a[i] + v1a[i]) * rinv);
        r.u[i + 4] = f2bf_hw((v0b[i] + v1b[i]) * rinv);
    }
    *(uint4*)(Qb + (size_t)rr * 64 + d0) = r.v;
}

// ---------- 5. output projection (MFMA, bf16 Wo), dbuf + 2x2 wave retile ----------
__global__ __launch_bounds__(256) void out_proj(
    const unsigned short* __restrict__ AObf, const unsigned short* __restrict__ Wobf,
    const float* __restrict__ bo, float* __restrict__ out) {
    const int m0 = blockIdx.y * 64;
    const int n0 = blockIdx.x * 64;
    const int b = m0 >> 10, tt0 = m0 & 1023;
    __shared__ __align__(16) unsigned short As[2][64][72];
    __shared__ __align__(16) unsigned short Bs[2][64][72];
    int tid = threadIdx.x, wave = tid >> 6, lane = tid & 63, quad = lane >> 4, l16 = lane & 15;
    const int wr = (wave >> 1) * 32, wc = (wave & 1) * 32;
    int c0 = tid, c1 = tid + 256;
    int r0 = c0 >> 3, kc0 = (c0 & 7) << 3;
    int r1 = c1 >> 3, kc1 = (c1 & 7) << 3;

    // prefetch k0 = 0 (h = 0)
    uint4 ar0 = *(const uint4*)(AObf + (((size_t)(b * 8 + 0) * 1024 + tt0 + r0) << 6) + kc0);
    uint4 ar1 = *(const uint4*)(AObf + (((size_t)(b * 8 + 0) * 1024 + tt0 + r1) << 6) + kc1);
    uint4 br0 = *(const uint4*)(Wobf + (size_t)(n0 + r0) * 512 + kc0);
    uint4 br1 = *(const uint4*)(Wobf + (size_t)(n0 + r1) * 512 + kc1);

    f32x4 acc[2][2] = {};
    int p = 0;
    for (int k0 = 0; k0 < 512; k0 += 64) {
        *(uint4*)(&As[p][r0][kc0]) = ar0;
        *(uint4*)(&As[p][r1][kc1]) = ar1;
        *(uint4*)(&Bs[p][r0][kc0]) = br0;
        *(uint4*)(&Bs[p][r1][kc1]) = br1;
        int kn = k0 + 64;
        if (kn < 512) {
            int h = kn >> 6;
            ar0 = *(const uint4*)(AObf + (((size_t)(b * 8 + h) * 1024 + tt0 + r0) << 6) + kc0);
            ar1 = *(const uint4*)(AObf + (((size_t)(b * 8 + h) * 1024 + tt0 + r1) << 6) + kc1);
            br0 = *(const uint4*)(Wobf + (size_t)(n0 + r0) * 512 + kn + kc0);
            br1 = *(const uint4*)(Wobf + (size_t)(n0 + r1) * 512 + kn + kc1);
        }
        __syncthreads();   // buffer p staged; sole barrier this iteration
        for (int kk = 0; kk < 2; ++kk) {
            bf16x8 af0 = *(const bf16x8*)(&As[p][wr + l16][kk * 32 + quad * 8]);
            bf16x8 af1 = *(const bf16x8*)(&As[p][wr + 16 + l16][kk * 32 + quad * 8]);
            bf16x8 b0 = *(const bf16x8*)(&Bs[p][wc + l16][kk * 32 + quad * 8]);
            bf16x8 b1 = *(const bf16x8*)(&Bs[p][wc + 16 + l16][kk * 32 + quad * 8]);
            acc[0][0] = MFMA16(af0, b0, acc[0][0]);
            acc[0][1] = MFMA16(af0, b1, acc[0][1]);
            acc[1][0] = MFMA16(af1, b0, acc[1][0]);
            acc[1][1] = MFMA16(af1, b1, acc[1][1]);
        }
        p ^= 1;
    }
    for (int ni = 0; ni < 2; ++ni) {
        int col = n0 + wc + ni * 16 + l16;
        float bv_ = bo[col];
        for (int mi = 0; mi < 2; ++mi)
            for (int reg = 0; reg < 4; ++reg) {
                int row = m0 + wr + mi * 16 + quad * 4 + reg;
                out[(size_t)row * 512 + col] = acc[mi][ni][reg] + bv_;
            }
    }
}

extern "C" void kernel_launch(void* const* d_in, const int* in_sizes, int n_in,
                              void* d_out, int out_size, void* d_ws, size_t ws_size,
                              hipStream_t stream) {
    const void* x = nullptr; const void* Ws[4] = {}; const void* bs[4] = {};
    const void* relT = nullptr;
    int wi = 0, bi = 0, idx_x = -1;
    for (int i = 0; i < n_in; ++i) {
        long s = in_sizes[i];
        if ((s == 2097152 || s == 8388608) && !x) { x = d_in[i]; idx_x = i; }
        else if ((s == 262144 || s == 1048576) && wi < 4) Ws[wi++] = d_in[i];
        else if ((s == 512 || s == 2048) && bi < 4) bs[bi++] = d_in[i];
        else if ((s == 32832 || s == 131328) && !relT) relT = d_in[i];
    }
    const float *Wq, *Wk, *Wv, *Wo, *bq, *bk, *bv, *bo;
    if (x && wi == 4 && bi == 4 && relT) {
        bool sorted_order = (idx_x != 0);    // measured: dict order (idx_x==0)
        if (sorted_order) {
            Wq = (const float*)Ws[2]; Wk = (const float*)Ws[0];
            Wv = (const float*)Ws[3]; Wo = (const float*)Ws[1];
            bq = (const float*)bs[2]; bk = (const float*)bs[0];
            bv = (const float*)bs[3]; bo = (const float*)bs[1];
        } else {
            Wq = (const float*)Ws[0]; Wk = (const float*)Ws[1];
            Wv = (const float*)Ws[2]; Wo = (const float*)Ws[3];
            bq = (const float*)bs[0]; bk = (const float*)bs[1];
            bv = (const float*)bs[2]; bo = (const float*)bs[3];
        }
    } else {
        x = d_in[0];
        Wq = (const float*)d_in[2]; bq = (const float*)d_in[3];
        Wk = (const float*)d_in[4]; bk = (const float*)d_in[5];
        Wv = (const float*)d_in[6]; bv = (const float*)d_in[7];
        Wo = (const float*)d_in[8]; bo = (const float*)d_in[9];
        relT = d_in[10];
    }
    const float* xf  = (const float*)x;
    const float* rel = (const float*)relT;
    float* out = (float*)d_out;

    // ws: hdr 128K | Qb/Kb/VbT 3x4M | part 256K | pad 128K | Wbf 2M | xbf 4M |
    //     accoP 16M | lsumP 256K  (~35 MiB total)
    char* ws = (char*)d_ws;
    float* Qsum = (float*)(ws + 8192);
    float* Rbuf = (float*)(ws + 16384);
    unsigned short* Qb  = (unsigned short*)(ws + 131072);
    unsigned short* Kb  = (unsigned short*)(ws + 131072 + (4 << 20));
    unsigned short* VbT = (unsigned short*)(ws + 131072 + (8 << 20));
    char* tail = ws + 131072 + (12 << 20);
    float* part = (float*)(tail);                        // 256 KB
    unsigned short* Wbf = (unsigned short*)(tail + 262144 + 131072);          // 2 MiB
    unsigned short* xbf = (unsigned short*)(tail + 262144 + 131072 + (2 << 20)); // 4 MiB
    char* tail2 = tail + 262144 + 131072 + (2 << 20) + (4 << 20);
    float* accoP = (float*)(tail2);                      // 2 x 8 MiB
    float* lsumP = (float*)(tail2 + (16 << 20));         // 2 x 128 KB

    prep_kernel<<<dim3(3200), dim3(256), 0, stream>>>(Wq, Wk, Wv, Wo, xf, Wbf, xbf, part);
    qkvq_fused<<<dim3(8, 128), dim3(256), 0, stream>>>(xbf, Wbf, bq, bk, bv, Qb, Kb, VbT,
                                                       part, Wq, Qsum);
    rbias_kernel<<<dim3(4104), dim3(256), 0, stream>>>(Qsum, rel, Rbuf);
    attn_kernel<<<dim3(16, 32, 2), dim3(256), 0, stream>>>(Qb, Kb, VbT, Rbuf, accoP, lsumP);
    attn_combine<<<dim3(1024), dim3(256), 0, stream>>>(accoP, lsumP, Qb);
    out_proj<<<dim3(8, 64), dim3(256), 0, stream>>>(Qb, Wbf + 3 * 262144, bo, out);
}

// Round 12
// 137.488 us; speedup vs baseline: 1.0567x; 1.0567x over previous
//
#include <hip/hip_runtime.h>
#include <stdint.h>

typedef __bf16  bf16x8 __attribute__((ext_vector_type(8)));
typedef float   f32x4  __attribute__((ext_vector_type(4)));

#define MFMA16(a, b, c) __builtin_amdgcn_mfma_f32_16x16x32_bf16((a), (b), (c), 0, 0, 0)

__device__ __forceinline__ float bf2f(unsigned short u) {
    union { unsigned u; float f; } v; v.u = ((unsigned)u) << 16; return v.f;
}
__device__ __forceinline__ unsigned short f2bf(float f) {
    union { float f; unsigned u; } v; v.f = f;
    unsigned r = v.u + 0x7fffu + ((v.u >> 16) & 1u);
    return (unsigned short)(r >> 16);
}
// native HW convert (v_cvt, RNE)
__device__ __forceinline__ unsigned short f2bf_hw(float f) {
    union { __bf16 h; unsigned short u; } v; v.h = (__bf16)f; return v.u;
}

// async global->LDS, 16B per lane. LDS dest is wave-uniform base + lane*16 (linear).
__device__ __forceinline__ void gload16(const unsigned short* g, unsigned short* l) {
    __builtin_amdgcn_global_load_lds(
        (const __attribute__((address_space(1))) unsigned int*)g,
        (__attribute__((address_space(3))) unsigned int*)l,
        16, 0, 0);
}

// B=4, T=1024, D=512, H=8, DH=64, MAX_REL=256. Inputs fp32 dict-order; OUTPUT FP32.
// R29: revert R28 (split-K partial-traffic cost > occupancy gain, +8.5us).
// Base = R27 (136.8us known-good). One change: T5 s_setprio(1) around attn's
// MFMA clusters (learn_hip m191: +4-7% attn within-probe; NOT applied to GEMMs,
// m190 null/negative on lockstep). Everything else byte-identical to R27.

// ---------- 1. prep: cast W,x fp32->bf16 AND x column-sum partials ----------
__global__ __launch_bounds__(256) void prep_kernel(const float* __restrict__ Wq,
                                                   const float* __restrict__ Wk,
                                                   const float* __restrict__ Wv,
                                                   const float* __restrict__ Wo,
                                                   const float* __restrict__ x,
                                                   unsigned short* __restrict__ Wbf,
                                                   unsigned short* __restrict__ xbf,
                                                   float* __restrict__ part) {
    int bid = blockIdx.x;
    if (bid < 1024) {             // weights: 262144 chunks of 4
        int idx = bid * 256 + threadIdx.x;
        int which = idx >> 16, off = (idx & 65535) << 2;
        const float* src = which == 0 ? Wq : which == 1 ? Wk : which == 2 ? Wv : Wo;
        f32x4 v = *(const f32x4*)(src + off);
        ushort4 r;
        r.x = f2bf(v[0]); r.y = f2bf(v[1]); r.z = f2bf(v[2]); r.w = f2bf(v[3]);
        *(ushort4*)(Wbf + (size_t)which * 262144 + off) = r;
    } else if (bid < 3072) {      // x: 524288 chunks of 4
        int cidx = (bid - 1024) * 256 + threadIdx.x;
        size_t off = (size_t)cidx << 2;
        f32x4 v = *(const f32x4*)(x + off);
        ushort4 r;
        r.x = f2bf(v[0]); r.y = f2bf(v[1]); r.z = f2bf(v[2]); r.w = f2bf(v[3]);
        *(ushort4*)(xbf + off) = r;
    } else {                      // xsum partials: 128 blocks = (4 b) x (32 chunks)
        int t = bid - 3072;
        int b = t >> 5, chunk = t & 31, k = threadIdx.x;
        const float* p = x + (size_t)b * 1024 * 512 + (size_t)chunk * 32 * 512;
        float s0 = 0.f, s1 = 0.f;
        for (int tt = 0; tt < 32; ++tt) {
            s0 += p[tt * 512 + k];
            s1 += p[tt * 512 + k + 256];
        }
        part[(size_t)(b * 32 + chunk) * 512 + k]       = s0;
        part[(size_t)(b * 32 + chunk) * 512 + k + 256] = s1;
    }
}

// ---------- 2. qkvq: FUSED QKV projection (y<64) + qsum reduction (y>=64) ----------
// Q written pre-scaled by 0.125*log2e (softmax fold); K/V unscaled.
__global__ __launch_bounds__(256) void qkvq_fused(
    const unsigned short* __restrict__ xbf, const unsigned short* __restrict__ Wbf,
    const float* __restrict__ bq, const float* __restrict__ bk, const float* __restrict__ bv,
    unsigned short* __restrict__ Qb, unsigned short* __restrict__ Kb,
    unsigned short* __restrict__ VbT,
    const float* __restrict__ part, const float* __restrict__ Wq,
    float* __restrict__ Qsum) {

    __shared__ __align__(16) unsigned short Tl[2][4][4096];   // [buf][tensor][64x64]

    int tid = threadIdx.x;

    if (blockIdx.y >= 64) {
        // ---- qsum role: 512 blocks; reuse Tl as float scratch ----
        float* xs = (float*)&Tl[0][0][0];
        int bid = (blockIdx.y - 64) * 8 + blockIdx.x;     // 0..511
        int b = bid >> 7, wave = tid >> 6, lane = tid & 63;
        int n = (bid & 127) * 4 + wave;
        for (int k = tid; k < 512; k += 256) {
            float s = 0.f;
            for (int c = 0; c < 32; ++c) s += part[(size_t)(b * 32 + c) * 512 + k];
            xs[k] = s;
        }
        __syncthreads();
        const float* w = Wq + (size_t)n * 512;
        float s = 0.f;
        for (int j = lane; j < 512; j += 64) s += xs[j] * w[j];
        for (int off = 32; off; off >>= 1) s += __shfl_xor(s, off, 64);
        if (lane == 0) Qsum[b * 512 + n] = s + 1024.0f * bq[n];
        return;
    }

    // ---- qkv role ----
    const int m0 = blockIdx.y * 64;
    const int n0 = blockIdx.x * 64;

    int wave = tid >> 6, lane = tid & 63, quad = lane >> 4, l16 = lane & 15;
    const int wr = (wave >> 1) * 32, wc = (wave & 1) * 32;   // 2x2 wave tiling

    // wave w stages tensor w: 0 = x-tile, 1..3 = Wq/Wk/Wv-tile
    const unsigned short* gbase = (wave == 0)
        ? xbf + (size_t)m0 * 512
        : Wbf + (size_t)(wave - 1) * 262144 + (size_t)n0 * 512;
    const int srow = lane >> 3;      // row within 8-row segment
    const int schunk = lane & 7;     // 16B chunk within row

    f32x4 acc[3][2][2] = {};

    // prologue: stage k0=0 into buffer 0
    {
        unsigned short* lb = &Tl[0][wave][0];
#pragma unroll
        for (int seg = 0; seg < 8; ++seg) {
            int row = seg * 8 + srow;
            int chunk = schunk ^ (row & 7);                 // inverse-swizzled source
            gload16(gbase + (size_t)row * 512 + chunk * 8, lb + seg * 512);
        }
    }

    int p = 0;
    for (int k0 = 0; k0 < 512; k0 += 64) {
        __syncthreads();             // buffer p landed (compiler drains vmcnt here)
        int kn = k0 + 64;
        if (kn < 512) {              // async-stage next tile; hidden under MFMAs below
            unsigned short* lb = &Tl[p ^ 1][wave][0];
#pragma unroll
            for (int seg = 0; seg < 8; ++seg) {
                int row = seg * 8 + srow;
                int chunk = schunk ^ (row & 7);
                gload16(gbase + (size_t)row * 512 + kn + chunk * 8, lb + seg * 512);
            }
        }
#pragma unroll
        for (int kk = 0; kk < 2; ++kk) {
            // read-side XOR: (wr|wc are multiples of 16 so row&7 == l16&7)
            int chk = (((kk * 4 + quad) ^ (l16 & 7)) << 3);
            bf16x8 af0 = *(const bf16x8*)(&Tl[p][0][(wr + l16) * 64 + chk]);
            bf16x8 af1 = *(const bf16x8*)(&Tl[p][0][(wr + 16 + l16) * 64 + chk]);
#pragma unroll
            for (int w = 0; w < 3; ++w) {
                bf16x8 b0 = *(const bf16x8*)(&Tl[p][1 + w][(wc + l16) * 64 + chk]);
                bf16x8 b1 = *(const bf16x8*)(&Tl[p][1 + w][(wc + 16 + l16) * 64 + chk]);
                acc[w][0][0] = MFMA16(af0, b0, acc[w][0][0]);
                acc[w][0][1] = MFMA16(af0, b1, acc[w][0][1]);
                acc[w][1][0] = MFMA16(af1, b0, acc[w][1][0]);
                acc[w][1][1] = MFMA16(af1, b1, acc[w][1][1]);
            }
        }
        p ^= 1;
    }

    // Q, K epilogue (C: row = m0+wr+mi*16+quad*4+reg, col = n0+wc+ni*16+l16)
    // Q pre-scaled by 0.125*log2e so attn's softmax drops the per-element mul.
    for (int w = 0; w < 2; ++w) {
        unsigned short* Out = (w == 0) ? Qb : Kb;
        const float* bias = (w == 0) ? bq : bk;
        const float scl = (w == 0) ? 0.18033688f : 1.0f;
        for (int ni = 0; ni < 2; ++ni) {
            int col = n0 + wc + ni * 16 + l16;
            int h = col >> 6, d = col & 63;
            float bv_ = bias[col];
            for (int mi = 0; mi < 2; ++mi)
                for (int reg = 0; reg < 4; ++reg) {
                    int row = m0 + wr + mi * 16 + quad * 4 + reg;   // = b*1024 + t
                    int b = row >> 10, t = row & 1023;
                    Out[(((size_t)(b * 8 + h) * 1024 + t) << 6) + d] =
                        f2bf((acc[w][mi][ni][reg] + bv_) * scl);
                }
        }
    }
    // V epilogue: transpose via LDS (reuse Tl[0], stride 72 => 144B rows, 16B-aligned)
    __syncthreads();
    unsigned short* Vt = &Tl[0][0][0];                     // [64][72]
    for (int ni = 0; ni < 2; ++ni) {
        int dl = wc + ni * 16 + l16;
        float bv_ = bv[n0 + dl];
        for (int mi = 0; mi < 2; ++mi)
            for (int reg = 0; reg < 4; ++reg)
                Vt[dl * 72 + wr + mi * 16 + quad * 4 + reg] = f2bf(acc[2][mi][ni][reg] + bv_);
    }
    __syncthreads();
    const int h = n0 >> 6, b = m0 >> 10, tg = m0 & 1023;
    for (int c = tid; c < 512; c += 256) {
        int dl = c >> 3, seg = (c & 7) << 3;
        *(uint4*)(VbT + (((size_t)((b * 8 + h) * 64 + dl)) << 10) + tg + seg) =
            *(const uint4*)(&Vt[dl * 72 + seg]);
    }
}

// ---------- 3. R bias (wave per output; 4104 blocks). Writes R * 0.125 * log2e ----------
__global__ __launch_bounds__(256) void rbias_kernel(const float* __restrict__ Qsum,
                                                    const float* __restrict__ relT,
                                                    float* __restrict__ R) {
    int idx = blockIdx.x * 4 + (threadIdx.x >> 6);
    if (idx >= 4 * 8 * 513) return;
    int lane = threadIdx.x & 63;
    int delta = idx % 513, bh = idx / 513;
    int b = bh >> 3, h = bh & 7;
    float s = Qsum[b * 512 + h * 64 + lane] * relT[(size_t)delta * 64 + lane];
    for (int off = 32; off; off >>= 1) s += __shfl_xor(s, off, 64);
    if (lane == 0) R[idx] = 0.18033688f * s;    // 0.125 * log2(e)
}

// ---------- 4. MFMA flash attention, tile-64, dbuf Ks/Vt, rmax folded in ----------
// Q arrives pre-scaled; R pre-scaled; softmax = exp2(accs + Rs[dlt] - m).
// T5: s_setprio(1) around MFMA clusters (2 blocks/CU at independent phases).
__global__ __launch_bounds__(256) void attn_kernel(
    unsigned short* __restrict__ Qb,
    const unsigned short* __restrict__ Kb, const unsigned short* __restrict__ VbT,
    const float* __restrict__ R) {
    const int bh = blockIdx.y;
    const int t0 = blockIdx.x * 64;
    __shared__ __align__(16) unsigned short Ks[2][64][72];
    __shared__ __align__(16) unsigned short Vt[2][64][72];
    __shared__ __align__(16) unsigned short Ps[64][72];
    __shared__ float Rs[513];
    __shared__ float Ms[64];

    int tid = threadIdx.x, wave = tid >> 6, lane = tid & 63, quad = lane >> 4, l16 = lane & 15;

    for (int i = tid; i < 513; i += 256) Rs[i] = R[bh * 513 + i];

    unsigned short* Qp = Qb + ((size_t)bh * 1024 + t0) * 64;
    int arow = wave * 16 + l16;
    bf16x8 qf0 = *(const bf16x8*)(Qp + arow * 64 + quad * 8);
    bf16x8 qf1 = *(const bf16x8*)(Qp + arow * 64 + 32 + quad * 8);

    const unsigned short* Kp  = Kb  + (size_t)bh * 65536;
    const unsigned short* Vtp = VbT + (size_t)bh * 65536;

    int c0 = tid, c1 = tid + 256;
    int r0 = c0 >> 3, kc0 = (c0 & 7) << 3;
    int r1 = c1 >> 3, kc1 = (c1 & 7) << 3;

    uint4 kreg0 = *(const uint4*)(Kp + (size_t)r0 * 64 + kc0);
    uint4 kreg1 = *(const uint4*)(Kp + (size_t)r1 * 64 + kc1);
    uint4 vreg0 = *(const uint4*)(Vtp + ((size_t)r0 << 10) + kc0);
    uint4 vreg1 = *(const uint4*)(Vtp + ((size_t)r1 << 10) + kc1);

    // ---- folded rmax: window max over staged Rs; 4 scanner threads per row ----
    __syncthreads();                      // Rs complete
    {
        int r = tid >> 2, q = tid & 3;    // 64 rows x 4 scanners (adjacent lanes)
        int t = t0 + r;
        int lo = 256 - (t < 256 ? t : 256);
        int hi = 256 + ((1023 - t) < 256 ? (1023 - t) : 256);
        float m = -3.4e38f;
        for (int j = lo + q; j <= hi; j += 4) m = fmaxf(m, Rs[j]);
        m = fmaxf(m, __shfl_xor(m, 1, 64));
        m = fmaxf(m, __shfl_xor(m, 2, 64));
        if (q == 0) Ms[r] = m;
    }
    __syncthreads();                      // Ms complete
    float mrow[4];
    for (int reg = 0; reg < 4; ++reg)
        mrow[reg] = Ms[wave * 16 + quad * 4 + reg];

    f32x4 acco[4] = {};
    float lsum[4] = {0.f, 0.f, 0.f, 0.f};
    int p = 0;

    for (int s0 = 0; s0 < 1024; s0 += 64) {
        *(uint4*)(&Ks[p][r0][kc0]) = kreg0;
        *(uint4*)(&Ks[p][r1][kc1]) = kreg1;
        *(uint4*)(&Vt[p][r0][kc0]) = vreg0;
        *(uint4*)(&Vt[p][r1][kc1]) = vreg1;
        int sn = s0 + 64;
        if (sn < 1024) {
            kreg0 = *(const uint4*)(Kp + (size_t)(sn + r0) * 64 + kc0);
            kreg1 = *(const uint4*)(Kp + (size_t)(sn + r1) * 64 + kc1);
            vreg0 = *(const uint4*)(Vtp + ((size_t)r0 << 10) + sn + kc0);
            vreg1 = *(const uint4*)(Vtp + ((size_t)r1 << 10) + sn + kc1);
        }
        __syncthreads();

        f32x4 accs[4] = {};
        __builtin_amdgcn_s_setprio(1);
        for (int nt = 0; nt < 4; ++nt) {
            bf16x8 kf0 = *(const bf16x8*)(&Ks[p][nt * 16 + l16][quad * 8]);
            accs[nt] = MFMA16(qf0, kf0, accs[nt]);
            bf16x8 kf1 = *(const bf16x8*)(&Ks[p][nt * 16 + l16][32 + quad * 8]);
            accs[nt] = MFMA16(qf1, kf1, accs[nt]);
        }
        __builtin_amdgcn_s_setprio(0);

        for (int reg = 0; reg < 4; ++reg) {
            int tt = t0 + wave * 16 + quad * 4 + reg;
            for (int nt = 0; nt < 4; ++nt) {
                int ss = s0 + nt * 16 + l16;
                int dlt = ss - tt;
                dlt = dlt > 256 ? 256 : (dlt < -256 ? -256 : dlt);
                // Q pre-scaled: score already in base-2 units
                float v = accs[nt][reg] + Rs[dlt + 256];
                float p_ = __builtin_amdgcn_exp2f(v - mrow[reg]);
                lsum[reg] += p_;
                Ps[wave * 16 + quad * 4 + reg][nt * 16 + l16] = f2bf_hw(p_);
            }
        }

        __builtin_amdgcn_s_setprio(1);
        for (int kk = 0; kk < 2; ++kk) {
            bf16x8 pf = *(const bf16x8*)(&Ps[wave * 16 + l16][kk * 32 + quad * 8]);
            for (int nt = 0; nt < 4; ++nt) {
                bf16x8 vf = *(const bf16x8*)(&Vt[p][nt * 16 + l16][kk * 32 + quad * 8]);
                acco[nt] = MFMA16(pf, vf, acco[nt]);
            }
        }
        __builtin_amdgcn_s_setprio(0);
        p ^= 1;
    }

    for (int reg = 0; reg < 4; ++reg)
        for (int off = 1; off < 16; off <<= 1) lsum[reg] += __shfl_xor(lsum[reg], off, 64);

    for (int nt = 0; nt < 4; ++nt) {
        for (int reg = 0; reg < 4; ++reg) {
            int tt = t0 + wave * 16 + quad * 4 + reg;
            int d = nt * 16 + l16;
            Qb[((size_t)bh * 1024 + tt) * 64 + d] = f2bf_hw(acco[nt][reg] / lsum[reg]);
        }
    }
}

// ---------- 5. output projection (MFMA, bf16 Wo), dbuf + 2x2 wave retile ----------
__global__ __launch_bounds__(256) void out_proj(
    const unsigned short* __restrict__ AObf, const unsigned short* __restrict__ Wobf,
    const float* __restrict__ bo, float* __restrict__ out) {
    const int m0 = blockIdx.y * 64;
    const int n0 = blockIdx.x * 64;
    const int b = m0 >> 10, tt0 = m0 & 1023;
    __shared__ __align__(16) unsigned short As[2][64][72];
    __shared__ __align__(16) unsigned short Bs[2][64][72];
    int tid = threadIdx.x, wave = tid >> 6, lane = tid & 63, quad = lane >> 4, l16 = lane & 15;
    const int wr = (wave >> 1) * 32, wc = (wave & 1) * 32;
    int c0 = tid, c1 = tid + 256;
    int r0 = c0 >> 3, kc0 = (c0 & 7) << 3;
    int r1 = c1 >> 3, kc1 = (c1 & 7) << 3;

    // prefetch k0 = 0 (h = 0)
    uint4 ar0 = *(const uint4*)(AObf + (((size_t)(b * 8 + 0) * 1024 + tt0 + r0) << 6) + kc0);
    uint4 ar1 = *(const uint4*)(AObf + (((size_t)(b * 8 + 0) * 1024 + tt0 + r1) << 6) + kc1);
    uint4 br0 = *(const uint4*)(Wobf + (size_t)(n0 + r0) * 512 + kc0);
    uint4 br1 = *(const uint4*)(Wobf + (size_t)(n0 + r1) * 512 + kc1);

    f32x4 acc[2][2] = {};
    int p = 0;
    for (int k0 = 0; k0 < 512; k0 += 64) {
        *(uint4*)(&As[p][r0][kc0]) = ar0;
        *(uint4*)(&As[p][r1][kc1]) = ar1;
        *(uint4*)(&Bs[p][r0][kc0]) = br0;
        *(uint4*)(&Bs[p][r1][kc1]) = br1;
        int kn = k0 + 64;
        if (kn < 512) {
            int h = kn >> 6;
            ar0 = *(const uint4*)(AObf + (((size_t)(b * 8 + h) * 1024 + tt0 + r0) << 6) + kc0);
            ar1 = *(const uint4*)(AObf + (((size_t)(b * 8 + h) * 1024 + tt0 + r1) << 6) + kc1);
            br0 = *(const uint4*)(Wobf + (size_t)(n0 + r0) * 512 + kn + kc0);
            br1 = *(const uint4*)(Wobf + (size_t)(n0 + r1) * 512 + kn + kc1);
        }
        __syncthreads();   // buffer p staged; sole barrier this iteration
        for (int kk = 0; kk < 2; ++kk) {
            bf16x8 af0 = *(const bf16x8*)(&As[p][wr + l16][kk * 32 + quad * 8]);
            bf16x8 af1 = *(const bf16x8*)(&As[p][wr + 16 + l16][kk * 32 + quad * 8]);
            bf16x8 b0 = *(const bf16x8*)(&Bs[p][wc + l16][kk * 32 + quad * 8]);
            bf16x8 b1 = *(const bf16x8*)(&Bs[p][wc + 16 + l16][kk * 32 + quad * 8]);
            acc[0][0] = MFMA16(af0, b0, acc[0][0]);
            acc[0][1] = MFMA16(af0, b1, acc[0][1]);
            acc[1][0] = MFMA16(af1, b0, acc[1][0]);
            acc[1][1] = MFMA16(af1, b1, acc[1][1]);
        }
        p ^= 1;
    }
    for (int ni = 0; ni < 2; ++ni) {
        int col = n0 + wc + ni * 16 + l16;
        float bv_ = bo[col];
        for (int mi = 0; mi < 2; ++mi)
            for (int reg = 0; reg < 4; ++reg) {
                int row = m0 + wr + mi * 16 + quad * 4 + reg;
                out[(size_t)row * 512 + col] = acc[mi][ni][reg] + bv_;
            }
    }
}

extern "C" void kernel_launch(void* const* d_in, const int* in_sizes, int n_in,
                              void* d_out, int out_size, void* d_ws, size_t ws_size,
                              hipStream_t stream) {
    const void* x = nullptr; const void* Ws[4] = {}; const void* bs[4] = {};
    const void* relT = nullptr;
    int wi = 0, bi = 0, idx_x = -1;
    for (int i = 0; i < n_in; ++i) {
        long s = in_sizes[i];
        if ((s == 2097152 || s == 8388608) && !x) { x = d_in[i]; idx_x = i; }
        else if ((s == 262144 || s == 1048576) && wi < 4) Ws[wi++] = d_in[i];
        else if ((s == 512 || s == 2048) && bi < 4) bs[bi++] = d_in[i];
        else if ((s == 32832 || s == 131328) && !relT) relT = d_in[i];
    }
    const float *Wq, *Wk, *Wv, *Wo, *bq, *bk, *bv, *bo;
    if (x && wi == 4 && bi == 4 && relT) {
        bool sorted_order = (idx_x != 0);    // measured: dict order (idx_x==0)
        if (sorted_order) {
            Wq = (const float*)Ws[2]; Wk = (const float*)Ws[0];
            Wv = (const float*)Ws[3]; Wo = (const float*)Ws[1];
            bq = (const float*)bs[2]; bk = (const float*)bs[0];
            bv = (const float*)bs[3]; bo = (const float*)bs[1];
        } else {
            Wq = (const float*)Ws[0]; Wk = (const float*)Ws[1];
            Wv = (const float*)Ws[2]; Wo = (const float*)Ws[3];
            bq = (const float*)bs[0]; bk = (const float*)bs[1];
            bv = (const float*)bs[2]; bo = (const float*)bs[3];
        }
    } else {
        x = d_in[0];
        Wq = (const float*)d_in[2]; bq = (const float*)d_in[3];
        Wk = (const float*)d_in[4]; bk = (const float*)d_in[5];
        Wv = (const float*)d_in[6]; bv = (const float*)d_in[7];
        Wo = (const float*)d_in[8]; bo = (const float*)d_in[9];
        relT = d_in[10];
    }
    const float* xf  = (const float*)x;
    const float* rel = (const float*)relT;
    float* out = (float*)d_out;

    // ws: hdr 128K | Qb/Kb/VbT 3x4M | part 256K | pad 128K | Wbf 2M | xbf 4M
    char* ws = (char*)d_ws;
    float* Qsum = (float*)(ws + 8192);
    float* Rbuf = (float*)(ws + 16384);
    unsigned short* Qb  = (unsigned short*)(ws + 131072);
    unsigned short* Kb  = (unsigned short*)(ws + 131072 + (4 << 20));
    unsigned short* VbT = (unsigned short*)(ws + 131072 + (8 << 20));
    char* tail = ws + 131072 + (12 << 20);
    float* part = (float*)(tail);                        // 256 KB
    unsigned short* Wbf = (unsigned short*)(tail + 262144 + 131072);          // 2 MiB
    unsigned short* xbf = (unsigned short*)(tail + 262144 + 131072 + (2 << 20)); // 4 MiB

    prep_kernel<<<dim3(3200), dim3(256), 0, stream>>>(Wq, Wk, Wv, Wo, xf, Wbf, xbf, part);
    qkvq_fused<<<dim3(8, 128), dim3(256), 0, stream>>>(xbf, Wbf, bq, bk, bv, Qb, Kb, VbT,
                                                       part, Wq, Qsum);
    rbias_kernel<<<dim3(4104), dim3(256), 0, stream>>>(Qsum, rel, Rbuf);
    attn_kernel<<<dim3(16, 32), dim3(256), 0, stream>>>(Qb, Kb, VbT, Rbuf);
    out_proj<<<dim3(8, 64), dim3(256), 0, stream>>>(Qb, Wbf + 3 * 262144, bo, out);
}

// Round 13
// 135.524 us; speedup vs baseline: 1.0720x; 1.0145x over previous
//
#include <hip/hip_runtime.h>
#include <stdint.h>

typedef __bf16  bf16x8 __attribute__((ext_vector_type(8)));
typedef float   f32x4  __attribute__((ext_vector_type(4)));

#define MFMA16(a, b, c) __builtin_amdgcn_mfma_f32_16x16x32_bf16((a), (b), (c), 0, 0, 0)

__device__ __forceinline__ float bf2f(unsigned short u) {
    union { unsigned u; float f; } v; v.u = ((unsigned)u) << 16; return v.f;
}
__device__ __forceinline__ unsigned short f2bf(float f) {
    union { float f; unsigned u; } v; v.f = f;
    unsigned r = v.u + 0x7fffu + ((v.u >> 16) & 1u);
    return (unsigned short)(r >> 16);
}
// native HW convert (v_cvt, RNE)
__device__ __forceinline__ unsigned short f2bf_hw(float f) {
    union { __bf16 h; unsigned short u; } v; v.h = (__bf16)f; return v.u;
}

// async global->LDS, 16B per lane. LDS dest is wave-uniform base + lane*16 (linear).
__device__ __forceinline__ void gload16(const unsigned short* g, unsigned short* l) {
    __builtin_amdgcn_global_load_lds(
        (const __attribute__((address_space(1))) unsigned int*)g,
        (__attribute__((address_space(3))) unsigned int*)l,
        16, 0, 0);
}

// B=4, T=1024, D=512, H=8, DH=64, MAX_REL=256. Inputs fp32 dict-order; OUTPUT FP32.
// R30: base = R27 (136.8us; setprio reverted — R29 null). Two changes, both attn:
//  (1) T1 XCD swizzle: 1D grid 512, bh=(id&7)*4+((id>>3)&3), t0=(id>>5)*64 —
//      the 16 blocks sharing one bh's K/V (256KB) land on ONE XCD's L2
//      (L3 ~500cy -> L2 ~200cy on the latency-critical staging loads).
//  (2) epilogue v_rcp + mul instead of 16 divides/thread.

// ---------- 1. prep: cast W,x fp32->bf16 AND x column-sum partials ----------
__global__ __launch_bounds__(256) void prep_kernel(const float* __restrict__ Wq,
                                                   const float* __restrict__ Wk,
                                                   const float* __restrict__ Wv,
                                                   const float* __restrict__ Wo,
                                                   const float* __restrict__ x,
                                                   unsigned short* __restrict__ Wbf,
                                                   unsigned short* __restrict__ xbf,
                                                   float* __restrict__ part) {
    int bid = blockIdx.x;
    if (bid < 1024) {             // weights: 262144 chunks of 4
        int idx = bid * 256 + threadIdx.x;
        int which = idx >> 16, off = (idx & 65535) << 2;
        const float* src = which == 0 ? Wq : which == 1 ? Wk : which == 2 ? Wv : Wo;
        f32x4 v = *(const f32x4*)(src + off);
        ushort4 r;
        r.x = f2bf(v[0]); r.y = f2bf(v[1]); r.z = f2bf(v[2]); r.w = f2bf(v[3]);
        *(ushort4*)(Wbf + (size_t)which * 262144 + off) = r;
    } else if (bid < 3072) {      // x: 524288 chunks of 4
        int cidx = (bid - 1024) * 256 + threadIdx.x;
        size_t off = (size_t)cidx << 2;
        f32x4 v = *(const f32x4*)(x + off);
        ushort4 r;
        r.x = f2bf(v[0]); r.y = f2bf(v[1]); r.z = f2bf(v[2]); r.w = f2bf(v[3]);
        *(ushort4*)(xbf + off) = r;
    } else {                      // xsum partials: 128 blocks = (4 b) x (32 chunks)
        int t = bid - 3072;
        int b = t >> 5, chunk = t & 31, k = threadIdx.x;
        const float* p = x + (size_t)b * 1024 * 512 + (size_t)chunk * 32 * 512;
        float s0 = 0.f, s1 = 0.f;
        for (int tt = 0; tt < 32; ++tt) {
            s0 += p[tt * 512 + k];
            s1 += p[tt * 512 + k + 256];
        }
        part[(size_t)(b * 32 + chunk) * 512 + k]       = s0;
        part[(size_t)(b * 32 + chunk) * 512 + k + 256] = s1;
    }
}

// ---------- 2. qkvq: FUSED QKV projection (y<64) + qsum reduction (y>=64) ----------
// Q written pre-scaled by 0.125*log2e (softmax fold); K/V unscaled.
__global__ __launch_bounds__(256) void qkvq_fused(
    const unsigned short* __restrict__ xbf, const unsigned short* __restrict__ Wbf,
    const float* __restrict__ bq, const float* __restrict__ bk, const float* __restrict__ bv,
    unsigned short* __restrict__ Qb, unsigned short* __restrict__ Kb,
    unsigned short* __restrict__ VbT,
    const float* __restrict__ part, const float* __restrict__ Wq,
    float* __restrict__ Qsum) {

    __shared__ __align__(16) unsigned short Tl[2][4][4096];   // [buf][tensor][64x64]

    int tid = threadIdx.x;

    if (blockIdx.y >= 64) {
        // ---- qsum role: 512 blocks; reuse Tl as float scratch ----
        float* xs = (float*)&Tl[0][0][0];
        int bid = (blockIdx.y - 64) * 8 + blockIdx.x;     // 0..511
        int b = bid >> 7, wave = tid >> 6, lane = tid & 63;
        int n = (bid & 127) * 4 + wave;
        for (int k = tid; k < 512; k += 256) {
            float s = 0.f;
            for (int c = 0; c < 32; ++c) s += part[(size_t)(b * 32 + c) * 512 + k];
            xs[k] = s;
        }
        __syncthreads();
        const float* w = Wq + (size_t)n * 512;
        float s = 0.f;
        for (int j = lane; j < 512; j += 64) s += xs[j] * w[j];
        for (int off = 32; off; off >>= 1) s += __shfl_xor(s, off, 64);
        if (lane == 0) Qsum[b * 512 + n] = s + 1024.0f * bq[n];
        return;
    }

    // ---- qkv role ----
    const int m0 = blockIdx.y * 64;
    const int n0 = blockIdx.x * 64;

    int wave = tid >> 6, lane = tid & 63, quad = lane >> 4, l16 = lane & 15;
    const int wr = (wave >> 1) * 32, wc = (wave & 1) * 32;   // 2x2 wave tiling

    // wave w stages tensor w: 0 = x-tile, 1..3 = Wq/Wk/Wv-tile
    const unsigned short* gbase = (wave == 0)
        ? xbf + (size_t)m0 * 512
        : Wbf + (size_t)(wave - 1) * 262144 + (size_t)n0 * 512;
    const int srow = lane >> 3;      // row within 8-row segment
    const int schunk = lane & 7;     // 16B chunk within row

    f32x4 acc[3][2][2] = {};

    // prologue: stage k0=0 into buffer 0
    {
        unsigned short* lb = &Tl[0][wave][0];
#pragma unroll
        for (int seg = 0; seg < 8; ++seg) {
            int row = seg * 8 + srow;
            int chunk = schunk ^ (row & 7);                 // inverse-swizzled source
            gload16(gbase + (size_t)row * 512 + chunk * 8, lb + seg * 512);
        }
    }

    int p = 0;
    for (int k0 = 0; k0 < 512; k0 += 64) {
        __syncthreads();             // buffer p landed (compiler drains vmcnt here)
        int kn = k0 + 64;
        if (kn < 512) {              // async-stage next tile; hidden under MFMAs below
            unsigned short* lb = &Tl[p ^ 1][wave][0];
#pragma unroll
            for (int seg = 0; seg < 8; ++seg) {
                int row = seg * 8 + srow;
                int chunk = schunk ^ (row & 7);
                gload16(gbase + (size_t)row * 512 + kn + chunk * 8, lb + seg * 512);
            }
        }
#pragma unroll
        for (int kk = 0; kk < 2; ++kk) {
            // read-side XOR: (wr|wc are multiples of 16 so row&7 == l16&7)
            int chk = (((kk * 4 + quad) ^ (l16 & 7)) << 3);
            bf16x8 af0 = *(const bf16x8*)(&Tl[p][0][(wr + l16) * 64 + chk]);
            bf16x8 af1 = *(const bf16x8*)(&Tl[p][0][(wr + 16 + l16) * 64 + chk]);
#pragma unroll
            for (int w = 0; w < 3; ++w) {
                bf16x8 b0 = *(const bf16x8*)(&Tl[p][1 + w][(wc + l16) * 64 + chk]);
                bf16x8 b1 = *(const bf16x8*)(&Tl[p][1 + w][(wc + 16 + l16) * 64 + chk]);
                acc[w][0][0] = MFMA16(af0, b0, acc[w][0][0]);
                acc[w][0][1] = MFMA16(af0, b1, acc[w][0][1]);
                acc[w][1][0] = MFMA16(af1, b0, acc[w][1][0]);
                acc[w][1][1] = MFMA16(af1, b1, acc[w][1][1]);
            }
        }
        p ^= 1;
    }

    // Q, K epilogue (C: row = m0+wr+mi*16+quad*4+reg, col = n0+wc+ni*16+l16)
    // Q pre-scaled by 0.125*log2e so attn's softmax drops the per-element mul.
    for (int w = 0; w < 2; ++w) {
        unsigned short* Out = (w == 0) ? Qb : Kb;
        const float* bias = (w == 0) ? bq : bk;
        const float scl = (w == 0) ? 0.18033688f : 1.0f;
        for (int ni = 0; ni < 2; ++ni) {
            int col = n0 + wc + ni * 16 + l16;
            int h = col >> 6, d = col & 63;
            float bv_ = bias[col];
            for (int mi = 0; mi < 2; ++mi)
                for (int reg = 0; reg < 4; ++reg) {
                    int row = m0 + wr + mi * 16 + quad * 4 + reg;   // = b*1024 + t
                    int b = row >> 10, t = row & 1023;
                    Out[(((size_t)(b * 8 + h) * 1024 + t) << 6) + d] =
                        f2bf((acc[w][mi][ni][reg] + bv_) * scl);
                }
        }
    }
    // V epilogue: transpose via LDS (reuse Tl[0], stride 72 => 144B rows, 16B-aligned)
    __syncthreads();
    unsigned short* Vt = &Tl[0][0][0];                     // [64][72]
    for (int ni = 0; ni < 2; ++ni) {
        int dl = wc + ni * 16 + l16;
        float bv_ = bv[n0 + dl];
        for (int mi = 0; mi < 2; ++mi)
            for (int reg = 0; reg < 4; ++reg)
                Vt[dl * 72 + wr + mi * 16 + quad * 4 + reg] = f2bf(acc[2][mi][ni][reg] + bv_);
    }
    __syncthreads();
    const int h = n0 >> 6, b = m0 >> 10, tg = m0 & 1023;
    for (int c = tid; c < 512; c += 256) {
        int dl = c >> 3, seg = (c & 7) << 3;
        *(uint4*)(VbT + (((size_t)((b * 8 + h) * 64 + dl)) << 10) + tg + seg) =
            *(const uint4*)(&Vt[dl * 72 + seg]);
    }
}

// ---------- 3. R bias (wave per output; 4104 blocks). Writes R * 0.125 * log2e ----------
__global__ __launch_bounds__(256) void rbias_kernel(const float* __restrict__ Qsum,
                                                    const float* __restrict__ relT,
                                                    float* __restrict__ R) {
    int idx = blockIdx.x * 4 + (threadIdx.x >> 6);
    if (idx >= 4 * 8 * 513) return;
    int lane = threadIdx.x & 63;
    int delta = idx % 513, bh = idx / 513;
    int b = bh >> 3, h = bh & 7;
    float s = Qsum[b * 512 + h * 64 + lane] * relT[(size_t)delta * 64 + lane];
    for (int off = 32; off; off >>= 1) s += __shfl_xor(s, off, 64);
    if (lane == 0) R[idx] = 0.18033688f * s;    // 0.125 * log2(e)
}

// ---------- 4. MFMA flash attention, tile-64, dbuf Ks/Vt, rmax folded in ----------
// Q arrives pre-scaled; R pre-scaled; softmax = exp2(accs + Rs[dlt] - m).
// 1D grid 512 with XCD swizzle: the 16 t-blocks of each bh share one XCD's L2.
__global__ __launch_bounds__(256) void attn_kernel(
    unsigned short* __restrict__ Qb,
    const unsigned short* __restrict__ Kb, const unsigned short* __restrict__ VbT,
    const float* __restrict__ R) {
    const int id = blockIdx.x;
    const int bh = (id & 7) * 4 + ((id >> 3) & 3);   // all 16 blocks of bh: same id%8
    const int t0 = (id >> 5) * 64;
    __shared__ __align__(16) unsigned short Ks[2][64][72];
    __shared__ __align__(16) unsigned short Vt[2][64][72];
    __shared__ __align__(16) unsigned short Ps[64][72];
    __shared__ float Rs[513];
    __shared__ float Ms[64];

    int tid = threadIdx.x, wave = tid >> 6, lane = tid & 63, quad = lane >> 4, l16 = lane & 15;

    for (int i = tid; i < 513; i += 256) Rs[i] = R[bh * 513 + i];

    unsigned short* Qp = Qb + ((size_t)bh * 1024 + t0) * 64;
    int arow = wave * 16 + l16;
    bf16x8 qf0 = *(const bf16x8*)(Qp + arow * 64 + quad * 8);
    bf16x8 qf1 = *(const bf16x8*)(Qp + arow * 64 + 32 + quad * 8);

    const unsigned short* Kp  = Kb  + (size_t)bh * 65536;
    const unsigned short* Vtp = VbT + (size_t)bh * 65536;

    int c0 = tid, c1 = tid + 256;
    int r0 = c0 >> 3, kc0 = (c0 & 7) << 3;
    int r1 = c1 >> 3, kc1 = (c1 & 7) << 3;

    uint4 kreg0 = *(const uint4*)(Kp + (size_t)r0 * 64 + kc0);
    uint4 kreg1 = *(const uint4*)(Kp + (size_t)r1 * 64 + kc1);
    uint4 vreg0 = *(const uint4*)(Vtp + ((size_t)r0 << 10) + kc0);
    uint4 vreg1 = *(const uint4*)(Vtp + ((size_t)r1 << 10) + kc1);

    // ---- folded rmax: window max over staged Rs; 4 scanner threads per row ----
    __syncthreads();                      // Rs complete
    {
        int r = tid >> 2, q = tid & 3;    // 64 rows x 4 scanners (adjacent lanes)
        int t = t0 + r;
        int lo = 256 - (t < 256 ? t : 256);
        int hi = 256 + ((1023 - t) < 256 ? (1023 - t) : 256);
        float m = -3.4e38f;
        for (int j = lo + q; j <= hi; j += 4) m = fmaxf(m, Rs[j]);
        m = fmaxf(m, __shfl_xor(m, 1, 64));
        m = fmaxf(m, __shfl_xor(m, 2, 64));
        if (q == 0) Ms[r] = m;
    }
    __syncthreads();                      // Ms complete
    float mrow[4];
    for (int reg = 0; reg < 4; ++reg)
        mrow[reg] = Ms[wave * 16 + quad * 4 + reg];

    f32x4 acco[4] = {};
    float lsum[4] = {0.f, 0.f, 0.f, 0.f};
    int p = 0;

    for (int s0 = 0; s0 < 1024; s0 += 64) {
        *(uint4*)(&Ks[p][r0][kc0]) = kreg0;
        *(uint4*)(&Ks[p][r1][kc1]) = kreg1;
        *(uint4*)(&Vt[p][r0][kc0]) = vreg0;
        *(uint4*)(&Vt[p][r1][kc1]) = vreg1;
        int sn = s0 + 64;
        if (sn < 1024) {
            kreg0 = *(const uint4*)(Kp + (size_t)(sn + r0) * 64 + kc0);
            kreg1 = *(const uint4*)(Kp + (size_t)(sn + r1) * 64 + kc1);
            vreg0 = *(const uint4*)(Vtp + ((size_t)r0 << 10) + sn + kc0);
            vreg1 = *(const uint4*)(Vtp + ((size_t)r1 << 10) + sn + kc1);
        }
        __syncthreads();

        f32x4 accs[4] = {};
        for (int nt = 0; nt < 4; ++nt) {
            bf16x8 kf0 = *(const bf16x8*)(&Ks[p][nt * 16 + l16][quad * 8]);
            accs[nt] = MFMA16(qf0, kf0, accs[nt]);
            bf16x8 kf1 = *(const bf16x8*)(&Ks[p][nt * 16 + l16][32 + quad * 8]);
            accs[nt] = MFMA16(qf1, kf1, accs[nt]);
        }

        for (int reg = 0; reg < 4; ++reg) {
            int tt = t0 + wave * 16 + quad * 4 + reg;
            for (int nt = 0; nt < 4; ++nt) {
                int ss = s0 + nt * 16 + l16;
                int dlt = ss - tt;
                dlt = dlt > 256 ? 256 : (dlt < -256 ? -256 : dlt);
                // Q pre-scaled: score already in base-2 units
                float v = accs[nt][reg] + Rs[dlt + 256];
                float p_ = __builtin_amdgcn_exp2f(v - mrow[reg]);
                lsum[reg] += p_;
                Ps[wave * 16 + quad * 4 + reg][nt * 16 + l16] = f2bf_hw(p_);
            }
        }

        for (int kk = 0; kk < 2; ++kk) {
            bf16x8 pf = *(const bf16x8*)(&Ps[wave * 16 + l16][kk * 32 + quad * 8]);
            for (int nt = 0; nt < 4; ++nt) {
                bf16x8 vf = *(const bf16x8*)(&Vt[p][nt * 16 + l16][kk * 32 + quad * 8]);
                acco[nt] = MFMA16(pf, vf, acco[nt]);
            }
        }
        p ^= 1;
    }

    for (int reg = 0; reg < 4; ++reg)
        for (int off = 1; off < 16; off <<= 1) lsum[reg] += __shfl_xor(lsum[reg], off, 64);

    // v_rcp + mul (1 ulp on normalization; 16 divides -> 4 rcp + 16 mul)
    float rinv[4];
    for (int reg = 0; reg < 4; ++reg) rinv[reg] = __builtin_amdgcn_rcpf(lsum[reg]);

    for (int nt = 0; nt < 4; ++nt) {
        for (int reg = 0; reg < 4; ++reg) {
            int tt = t0 + wave * 16 + quad * 4 + reg;
            int d = nt * 16 + l16;
            Qb[((size_t)bh * 1024 + tt) * 64 + d] = f2bf_hw(acco[nt][reg] * rinv[reg]);
        }
    }
}

// ---------- 5. output projection (MFMA, bf16 Wo), dbuf + 2x2 wave retile ----------
__global__ __launch_bounds__(256) void out_proj(
    const unsigned short* __restrict__ AObf, const unsigned short* __restrict__ Wobf,
    const float* __restrict__ bo, float* __restrict__ out) {
    const int m0 = blockIdx.y * 64;
    const int n0 = blockIdx.x * 64;
    const int b = m0 >> 10, tt0 = m0 & 1023;
    __shared__ __align__(16) unsigned short As[2][64][72];
    __shared__ __align__(16) unsigned short Bs[2][64][72];
    int tid = threadIdx.x, wave = tid >> 6, lane = tid & 63, quad = lane >> 4, l16 = lane & 15;
    const int wr = (wave >> 1) * 32, wc = (wave & 1) * 32;
    int c0 = tid, c1 = tid + 256;
    int r0 = c0 >> 3, kc0 = (c0 & 7) << 3;
    int r1 = c1 >> 3, kc1 = (c1 & 7) << 3;

    // prefetch k0 = 0 (h = 0)
    uint4 ar0 = *(const uint4*)(AObf + (((size_t)(b * 8 + 0) * 1024 + tt0 + r0) << 6) + kc0);
    uint4 ar1 = *(const uint4*)(AObf + (((size_t)(b * 8 + 0) * 1024 + tt0 + r1) << 6) + kc1);
    uint4 br0 = *(const uint4*)(Wobf + (size_t)(n0 + r0) * 512 + kc0);
    uint4 br1 = *(const uint4*)(Wobf + (size_t)(n0 + r1) * 512 + kc1);

    f32x4 acc[2][2] = {};
    int p = 0;
    for (int k0 = 0; k0 < 512; k0 += 64) {
        *(uint4*)(&As[p][r0][kc0]) = ar0;
        *(uint4*)(&As[p][r1][kc1]) = ar1;
        *(uint4*)(&Bs[p][r0][kc0]) = br0;
        *(uint4*)(&Bs[p][r1][kc1]) = br1;
        int kn = k0 + 64;
        if (kn < 512) {
            int h = kn >> 6;
            ar0 = *(const uint4*)(AObf + (((size_t)(b * 8 + h) * 1024 + tt0 + r0) << 6) + kc0);
            ar1 = *(const uint4*)(AObf + (((size_t)(b * 8 + h) * 1024 + tt0 + r1) << 6) + kc1);
            br0 = *(const uint4*)(Wobf + (size_t)(n0 + r0) * 512 + kn + kc0);
            br1 = *(const uint4*)(Wobf + (size_t)(n0 + r1) * 512 + kn + kc1);
        }
        __syncthreads();   // buffer p staged; sole barrier this iteration
        for (int kk = 0; kk < 2; ++kk) {
            bf16x8 af0 = *(const bf16x8*)(&As[p][wr + l16][kk * 32 + quad * 8]);
            bf16x8 af1 = *(const bf16x8*)(&As[p][wr + 16 + l16][kk * 32 + quad * 8]);
            bf16x8 b0 = *(const bf16x8*)(&Bs[p][wc + l16][kk * 32 + quad * 8]);
            bf16x8 b1 = *(const bf16x8*)(&Bs[p][wc + 16 + l16][kk * 32 + quad * 8]);
            acc[0][0] = MFMA16(af0, b0, acc[0][0]);
            acc[0][1] = MFMA16(af0, b1, acc[0][1]);
            acc[1][0] = MFMA16(af1, b0, acc[1][0]);
            acc[1][1] = MFMA16(af1, b1, acc[1][1]);
        }
        p ^= 1;
    }
    for (int ni = 0; ni < 2; ++ni) {
        int col = n0 + wc + ni * 16 + l16;
        float bv_ = bo[col];
        for (int mi = 0; mi < 2; ++mi)
            for (int reg = 0; reg < 4; ++reg) {
                int row = m0 + wr + mi * 16 + quad * 4 + reg;
                out[(size_t)row * 512 + col] = acc[mi][ni][reg] + bv_;
            }
    }
}

extern "C" void kernel_launch(void* const* d_in, const int* in_sizes, int n_in,
                              void* d_out, int out_size, void* d_ws, size_t ws_size,
                              hipStream_t stream) {
    const void* x = nullptr; const void* Ws[4] = {}; const void* bs[4] = {};
    const void* relT = nullptr;
    int wi = 0, bi = 0, idx_x = -1;
    for (int i = 0; i < n_in; ++i) {
        long s = in_sizes[i];
        if ((s == 2097152 || s == 8388608) && !x) { x = d_in[i]; idx_x = i; }
        else if ((s == 262144 || s == 1048576) && wi < 4) Ws[wi++] = d_in[i];
        else if ((s == 512 || s == 2048) && bi < 4) bs[bi++] = d_in[i];
        else if ((s == 32832 || s == 131328) && !relT) relT = d_in[i];
    }
    const float *Wq, *Wk, *Wv, *Wo, *bq, *bk, *bv, *bo;
    if (x && wi == 4 && bi == 4 && relT) {
        bool sorted_order = (idx_x != 0);    // measured: dict order (idx_x==0)
        if (sorted_order) {
            Wq = (const float*)Ws[2]; Wk = (const float*)Ws[0];
            Wv = (const float*)Ws[3]; Wo = (const float*)Ws[1];
            bq = (const float*)bs[2]; bk = (const float*)bs[0];
            bv = (const float*)bs[3]; bo = (const float*)bs[1];
        } else {
            Wq = (const float*)Ws[0]; Wk = (const float*)Ws[1];
            Wv = (const float*)Ws[2]; Wo = (const float*)Ws[3];
            bq = (const float*)bs[0]; bk = (const float*)bs[1];
            bv = (const float*)bs[2]; bo = (const float*)bs[3];
        }
    } else {
        x = d_in[0];
        Wq = (const float*)d_in[2]; bq = (const float*)d_in[3];
        Wk = (const float*)d_in[4]; bk = (const float*)d_in[5];
        Wv = (const float*)d_in[6]; bv = (const float*)d_in[7];
        Wo = (const float*)d_in[8]; bo = (const float*)d_in[9];
        relT = d_in[10];
    }
    const float* xf  = (const float*)x;
    const float* rel = (const float*)relT;
    float* out = (float*)d_out;

    // ws: hdr 128K | Qb/Kb/VbT 3x4M | part 256K | pad 128K | Wbf 2M | xbf 4M
    char* ws = (char*)d_ws;
    float* Qsum = (float*)(ws + 8192);
    float* Rbuf = (float*)(ws + 16384);
    unsigned short* Qb  = (unsigned short*)(ws + 131072);
    unsigned short* Kb  = (unsigned short*)(ws + 131072 + (4 << 20));
    unsigned short* VbT = (unsigned short*)(ws + 131072 + (8 << 20));
    char* tail = ws + 131072 + (12 << 20);
    float* part = (float*)(tail);                        // 256 KB
    unsigned short* Wbf = (unsigned short*)(tail + 262144 + 131072);          // 2 MiB
    unsigned short* xbf = (unsigned short*)(tail + 262144 + 131072 + (2 << 20)); // 4 MiB

    prep_kernel<<<dim3(3200), dim3(256), 0, stream>>>(Wq, Wk, Wv, Wo, xf, Wbf, xbf, part);
    qkvq_fused<<<dim3(8, 128), dim3(256), 0, stream>>>(xbf, Wbf, bq, bk, bv, Qb, Kb, VbT,
                                                       part, Wq, Qsum);
    rbias_kernel<<<dim3(4104), dim3(256), 0, stream>>>(Qsum, rel, Rbuf);
    attn_kernel<<<dim3(512), dim3(256), 0, stream>>>(Qb, Kb, VbT, Rbuf);
    out_proj<<<dim3(8, 64), dim3(256), 0, stream>>>(Qb, Wbf + 3 * 262144, bo, out);
}

// Round 14
// 133.054 us; speedup vs baseline: 1.0919x; 1.0186x over previous
//
#include <hip/hip_runtime.h>
#include <stdint.h>

typedef __bf16  bf16x8 __attribute__((ext_vector_type(8)));
typedef float   f32x4  __attribute__((ext_vector_type(4)));

#define MFMA16(a, b, c) __builtin_amdgcn_mfma_f32_16x16x32_bf16((a), (b), (c), 0, 0, 0)

__device__ __forceinline__ float bf2f(unsigned short u) {
    union { unsigned u; float f; } v; v.u = ((unsigned)u) << 16; return v.f;
}
__device__ __forceinline__ unsigned short f2bf(float f) {
    union { float f; unsigned u; } v; v.f = f;
    unsigned r = v.u + 0x7fffu + ((v.u >> 16) & 1u);
    return (unsigned short)(r >> 16);
}
// native HW convert (v_cvt, RNE)
__device__ __forceinline__ unsigned short f2bf_hw(float f) {
    union { __bf16 h; unsigned short u; } v; v.h = (__bf16)f; return v.u;
}

// async global->LDS, 16B per lane. LDS dest is wave-uniform base + lane*16 (linear).
__device__ __forceinline__ void gload16(const unsigned short* g, unsigned short* l) {
    __builtin_amdgcn_global_load_lds(
        (const __attribute__((address_space(1))) unsigned int*)g,
        (__attribute__((address_space(3))) unsigned int*)l,
        16, 0, 0);
}

// B=4, T=1024, D=512, H=8, DH=64, MAX_REL=256. Inputs fp32 dict-order; OUTPUT FP32.
// R31: base = R30 (135.5us best). Two micro-changes:
//  (1) attn rmax fast path: middle blocks (t0 in [256,704]) have the FULL window
//      [0,512] for every row -> M = one global max (parallel reduce), not 64
//      per-row 128-deep scans. Edge blocks keep the exact R30 path.
//  (2) qkv epilogue + prep converts use native v_cvt (f2bf_hw; RNE==RNE).

// ---------- 1. prep: cast W,x fp32->bf16 AND x column-sum partials ----------
__global__ __launch_bounds__(256) void prep_kernel(const float* __restrict__ Wq,
                                                   const float* __restrict__ Wk,
                                                   const float* __restrict__ Wv,
                                                   const float* __restrict__ Wo,
                                                   const float* __restrict__ x,
                                                   unsigned short* __restrict__ Wbf,
                                                   unsigned short* __restrict__ xbf,
                                                   float* __restrict__ part) {
    int bid = blockIdx.x;
    if (bid < 1024) {             // weights: 262144 chunks of 4
        int idx = bid * 256 + threadIdx.x;
        int which = idx >> 16, off = (idx & 65535) << 2;
        const float* src = which == 0 ? Wq : which == 1 ? Wk : which == 2 ? Wv : Wo;
        f32x4 v = *(const f32x4*)(src + off);
        ushort4 r;
        r.x = f2bf_hw(v[0]); r.y = f2bf_hw(v[1]); r.z = f2bf_hw(v[2]); r.w = f2bf_hw(v[3]);
        *(ushort4*)(Wbf + (size_t)which * 262144 + off) = r;
    } else if (bid < 3072) {      // x: 524288 chunks of 4
        int cidx = (bid - 1024) * 256 + threadIdx.x;
        size_t off = (size_t)cidx << 2;
        f32x4 v = *(const f32x4*)(x + off);
        ushort4 r;
        r.x = f2bf_hw(v[0]); r.y = f2bf_hw(v[1]); r.z = f2bf_hw(v[2]); r.w = f2bf_hw(v[3]);
        *(ushort4*)(xbf + off) = r;
    } else {                      // xsum partials: 128 blocks = (4 b) x (32 chunks)
        int t = bid - 3072;
        int b = t >> 5, chunk = t & 31, k = threadIdx.x;
        const float* p = x + (size_t)b * 1024 * 512 + (size_t)chunk * 32 * 512;
        float s0 = 0.f, s1 = 0.f;
        for (int tt = 0; tt < 32; ++tt) {
            s0 += p[tt * 512 + k];
            s1 += p[tt * 512 + k + 256];
        }
        part[(size_t)(b * 32 + chunk) * 512 + k]       = s0;
        part[(size_t)(b * 32 + chunk) * 512 + k + 256] = s1;
    }
}

// ---------- 2. qkvq: FUSED QKV projection (y<64) + qsum reduction (y>=64) ----------
// Q written pre-scaled by 0.125*log2e (softmax fold); K/V unscaled.
__global__ __launch_bounds__(256) void qkvq_fused(
    const unsigned short* __restrict__ xbf, const unsigned short* __restrict__ Wbf,
    const float* __restrict__ bq, const float* __restrict__ bk, const float* __restrict__ bv,
    unsigned short* __restrict__ Qb, unsigned short* __restrict__ Kb,
    unsigned short* __restrict__ VbT,
    const float* __restrict__ part, const float* __restrict__ Wq,
    float* __restrict__ Qsum) {

    __shared__ __align__(16) unsigned short Tl[2][4][4096];   // [buf][tensor][64x64]

    int tid = threadIdx.x;

    if (blockIdx.y >= 64) {
        // ---- qsum role: 512 blocks; reuse Tl as float scratch ----
        float* xs = (float*)&Tl[0][0][0];
        int bid = (blockIdx.y - 64) * 8 + blockIdx.x;     // 0..511
        int b = bid >> 7, wave = tid >> 6, lane = tid & 63;
        int n = (bid & 127) * 4 + wave;
        for (int k = tid; k < 512; k += 256) {
            float s = 0.f;
            for (int c = 0; c < 32; ++c) s += part[(size_t)(b * 32 + c) * 512 + k];
            xs[k] = s;
        }
        __syncthreads();
        const float* w = Wq + (size_t)n * 512;
        float s = 0.f;
        for (int j = lane; j < 512; j += 64) s += xs[j] * w[j];
        for (int off = 32; off; off >>= 1) s += __shfl_xor(s, off, 64);
        if (lane == 0) Qsum[b * 512 + n] = s + 1024.0f * bq[n];
        return;
    }

    // ---- qkv role ----
    const int m0 = blockIdx.y * 64;
    const int n0 = blockIdx.x * 64;

    int wave = tid >> 6, lane = tid & 63, quad = lane >> 4, l16 = lane & 15;
    const int wr = (wave >> 1) * 32, wc = (wave & 1) * 32;   // 2x2 wave tiling

    // wave w stages tensor w: 0 = x-tile, 1..3 = Wq/Wk/Wv-tile
    const unsigned short* gbase = (wave == 0)
        ? xbf + (size_t)m0 * 512
        : Wbf + (size_t)(wave - 1) * 262144 + (size_t)n0 * 512;
    const int srow = lane >> 3;      // row within 8-row segment
    const int schunk = lane & 7;     // 16B chunk within row

    f32x4 acc[3][2][2] = {};

    // prologue: stage k0=0 into buffer 0
    {
        unsigned short* lb = &Tl[0][wave][0];
#pragma unroll
        for (int seg = 0; seg < 8; ++seg) {
            int row = seg * 8 + srow;
            int chunk = schunk ^ (row & 7);                 // inverse-swizzled source
            gload16(gbase + (size_t)row * 512 + chunk * 8, lb + seg * 512);
        }
    }

    int p = 0;
    for (int k0 = 0; k0 < 512; k0 += 64) {
        __syncthreads();             // buffer p landed (compiler drains vmcnt here)
        int kn = k0 + 64;
        if (kn < 512) {              // async-stage next tile; hidden under MFMAs below
            unsigned short* lb = &Tl[p ^ 1][wave][0];
#pragma unroll
            for (int seg = 0; seg < 8; ++seg) {
                int row = seg * 8 + srow;
                int chunk = schunk ^ (row & 7);
                gload16(gbase + (size_t)row * 512 + kn + chunk * 8, lb + seg * 512);
            }
        }
#pragma unroll
        for (int kk = 0; kk < 2; ++kk) {
            // read-side XOR: (wr|wc are multiples of 16 so row&7 == l16&7)
            int chk = (((kk * 4 + quad) ^ (l16 & 7)) << 3);
            bf16x8 af0 = *(const bf16x8*)(&Tl[p][0][(wr + l16) * 64 + chk]);
            bf16x8 af1 = *(const bf16x8*)(&Tl[p][0][(wr + 16 + l16) * 64 + chk]);
#pragma unroll
            for (int w = 0; w < 3; ++w) {
                bf16x8 b0 = *(const bf16x8*)(&Tl[p][1 + w][(wc + l16) * 64 + chk]);
                bf16x8 b1 = *(const bf16x8*)(&Tl[p][1 + w][(wc + 16 + l16) * 64 + chk]);
                acc[w][0][0] = MFMA16(af0, b0, acc[w][0][0]);
                acc[w][0][1] = MFMA16(af0, b1, acc[w][0][1]);
                acc[w][1][0] = MFMA16(af1, b0, acc[w][1][0]);
                acc[w][1][1] = MFMA16(af1, b1, acc[w][1][1]);
            }
        }
        p ^= 1;
    }

    // Q, K epilogue (C: row = m0+wr+mi*16+quad*4+reg, col = n0+wc+ni*16+l16)
    // Q pre-scaled by 0.125*log2e so attn's softmax drops the per-element mul.
    for (int w = 0; w < 2; ++w) {
        unsigned short* Out = (w == 0) ? Qb : Kb;
        const float* bias = (w == 0) ? bq : bk;
        const float scl = (w == 0) ? 0.18033688f : 1.0f;
        for (int ni = 0; ni < 2; ++ni) {
            int col = n0 + wc + ni * 16 + l16;
            int h = col >> 6, d = col & 63;
            float bv_ = bias[col];
            for (int mi = 0; mi < 2; ++mi)
                for (int reg = 0; reg < 4; ++reg) {
                    int row = m0 + wr + mi * 16 + quad * 4 + reg;   // = b*1024 + t
                    int b = row >> 10, t = row & 1023;
                    Out[(((size_t)(b * 8 + h) * 1024 + t) << 6) + d] =
                        f2bf_hw((acc[w][mi][ni][reg] + bv_) * scl);
                }
        }
    }
    // V epilogue: transpose via LDS (reuse Tl[0], stride 72 => 144B rows, 16B-aligned)
    __syncthreads();
    unsigned short* Vt = &Tl[0][0][0];                     // [64][72]
    for (int ni = 0; ni < 2; ++ni) {
        int dl = wc + ni * 16 + l16;
        float bv_ = bv[n0 + dl];
        for (int mi = 0; mi < 2; ++mi)
            for (int reg = 0; reg < 4; ++reg)
                Vt[dl * 72 + wr + mi * 16 + quad * 4 + reg] = f2bf_hw(acc[2][mi][ni][reg] + bv_);
    }
    __syncthreads();
    const int h = n0 >> 6, b = m0 >> 10, tg = m0 & 1023;
    for (int c = tid; c < 512; c += 256) {
        int dl = c >> 3, seg = (c & 7) << 3;
        *(uint4*)(VbT + (((size_t)((b * 8 + h) * 64 + dl)) << 10) + tg + seg) =
            *(const uint4*)(&Vt[dl * 72 + seg]);
    }
}

// ---------- 3. R bias (wave per output; 4104 blocks). Writes R * 0.125 * log2e ----------
__global__ __launch_bounds__(256) void rbias_kernel(const float* __restrict__ Qsum,
                                                    const float* __restrict__ relT,
                                                    float* __restrict__ R) {
    int idx = blockIdx.x * 4 + (threadIdx.x >> 6);
    if (idx >= 4 * 8 * 513) return;
    int lane = threadIdx.x & 63;
    int delta = idx % 513, bh = idx / 513;
    int b = bh >> 3, h = bh & 7;
    float s = Qsum[b * 512 + h * 64 + lane] * relT[(size_t)delta * 64 + lane];
    for (int off = 32; off; off >>= 1) s += __shfl_xor(s, off, 64);
    if (lane == 0) R[idx] = 0.18033688f * s;    // 0.125 * log2(e)
}

// ---------- 4. MFMA flash attention, tile-64, dbuf Ks/Vt, rmax folded in ----------
// Q arrives pre-scaled; R pre-scaled; softmax = exp2(accs + Rs[dlt] - m).
// 1D grid 512 with XCD swizzle: the 16 t-blocks of each bh share one XCD's L2.
__global__ __launch_bounds__(256) void attn_kernel(
    unsigned short* __restrict__ Qb,
    const unsigned short* __restrict__ Kb, const unsigned short* __restrict__ VbT,
    const float* __restrict__ R) {
    const int id = blockIdx.x;
    const int bh = (id & 7) * 4 + ((id >> 3) & 3);   // all 16 blocks of bh: same id%8
    const int t0 = (id >> 5) * 64;
    __shared__ __align__(16) unsigned short Ks[2][64][72];
    __shared__ __align__(16) unsigned short Vt[2][64][72];
    __shared__ __align__(16) unsigned short Ps[64][72];
    __shared__ float Rs[513];
    __shared__ float Ms[64];

    int tid = threadIdx.x, wave = tid >> 6, lane = tid & 63, quad = lane >> 4, l16 = lane & 15;

    for (int i = tid; i < 513; i += 256) Rs[i] = R[bh * 513 + i];

    unsigned short* Qp = Qb + ((size_t)bh * 1024 + t0) * 64;
    int arow = wave * 16 + l16;
    bf16x8 qf0 = *(const bf16x8*)(Qp + arow * 64 + quad * 8);
    bf16x8 qf1 = *(const bf16x8*)(Qp + arow * 64 + 32 + quad * 8);

    const unsigned short* Kp  = Kb  + (size_t)bh * 65536;
    const unsigned short* Vtp = VbT + (size_t)bh * 65536;

    int c0 = tid, c1 = tid + 256;
    int r0 = c0 >> 3, kc0 = (c0 & 7) << 3;
    int r1 = c1 >> 3, kc1 = (c1 & 7) << 3;

    uint4 kreg0 = *(const uint4*)(Kp + (size_t)r0 * 64 + kc0);
    uint4 kreg1 = *(const uint4*)(Kp + (size_t)r1 * 64 + kc1);
    uint4 vreg0 = *(const uint4*)(Vtp + ((size_t)r0 << 10) + kc0);
    uint4 vreg1 = *(const uint4*)(Vtp + ((size_t)r1 << 10) + kc1);

    // ---- folded rmax ----
    __syncthreads();                      // Rs complete
    float mrow[4];
    if (t0 >= 256 && t0 <= 704) {
        // fast path: every row's window is the full [0,512] -> one global max
        float m = -3.4e38f;
        for (int j = tid; j <= 512; j += 256) m = fmaxf(m, Rs[j]);
        for (int off = 1; off < 64; off <<= 1) m = fmaxf(m, __shfl_xor(m, off, 64));
        if (lane == 0) Ms[wave] = m;
        __syncthreads();
        float g = fmaxf(fmaxf(Ms[0], Ms[1]), fmaxf(Ms[2], Ms[3]));
        for (int reg = 0; reg < 4; ++reg) mrow[reg] = g;
        __syncthreads();                  // Ms reuse-safe (none after, but keep order)
    } else {
        // edge path: per-row clipped window max; 4 scanner threads per row
        int r = tid >> 2, q = tid & 3;    // 64 rows x 4 scanners (adjacent lanes)
        int t = t0 + r;
        int lo = 256 - (t < 256 ? t : 256);
        int hi = 256 + ((1023 - t) < 256 ? (1023 - t) : 256);
        float m = -3.4e38f;
        for (int j = lo + q; j <= hi; j += 4) m = fmaxf(m, Rs[j]);
        m = fmaxf(m, __shfl_xor(m, 1, 64));
        m = fmaxf(m, __shfl_xor(m, 2, 64));
        if (q == 0) Ms[r] = m;
        __syncthreads();                  // Ms complete
        for (int reg = 0; reg < 4; ++reg)
            mrow[reg] = Ms[wave * 16 + quad * 4 + reg];
    }

    f32x4 acco[4] = {};
    float lsum[4] = {0.f, 0.f, 0.f, 0.f};
    int p = 0;

    for (int s0 = 0; s0 < 1024; s0 += 64) {
        *(uint4*)(&Ks[p][r0][kc0]) = kreg0;
        *(uint4*)(&Ks[p][r1][kc1]) = kreg1;
        *(uint4*)(&Vt[p][r0][kc0]) = vreg0;
        *(uint4*)(&Vt[p][r1][kc1]) = vreg1;
        int sn = s0 + 64;
        if (sn < 1024) {
            kreg0 = *(const uint4*)(Kp + (size_t)(sn + r0) * 64 + kc0);
            kreg1 = *(const uint4*)(Kp + (size_t)(sn + r1) * 64 + kc1);
            vreg0 = *(const uint4*)(Vtp + ((size_t)r0 << 10) + sn + kc0);
            vreg1 = *(const uint4*)(Vtp + ((size_t)r1 << 10) + sn + kc1);
        }
        __syncthreads();

        f32x4 accs[4] = {};
        for (int nt = 0; nt < 4; ++nt) {
            bf16x8 kf0 = *(const bf16x8*)(&Ks[p][nt * 16 + l16][quad * 8]);
            accs[nt] = MFMA16(qf0, kf0, accs[nt]);
            bf16x8 kf1 = *(const bf16x8*)(&Ks[p][nt * 16 + l16][32 + quad * 8]);
            accs[nt] = MFMA16(qf1, kf1, accs[nt]);
        }

        for (int reg = 0; reg < 4; ++reg) {
            int tt = t0 + wave * 16 + quad * 4 + reg;
            for (int nt = 0; nt < 4; ++nt) {
                int ss = s0 + nt * 16 + l16;
                int dlt = ss - tt;
                dlt = dlt > 256 ? 256 : (dlt < -256 ? -256 : dlt);
                // Q pre-scaled: score already in base-2 units
                float v = accs[nt][reg] + Rs[dlt + 256];
                float p_ = __builtin_amdgcn_exp2f(v - mrow[reg]);
                lsum[reg] += p_;
                Ps[wave * 16 + quad * 4 + reg][nt * 16 + l16] = f2bf_hw(p_);
            }
        }

        for (int kk = 0; kk < 2; ++kk) {
            bf16x8 pf = *(const bf16x8*)(&Ps[wave * 16 + l16][kk * 32 + quad * 8]);
            for (int nt = 0; nt < 4; ++nt) {
                bf16x8 vf = *(const bf16x8*)(&Vt[p][nt * 16 + l16][kk * 32 + quad * 8]);
                acco[nt] = MFMA16(pf, vf, acco[nt]);
            }
        }
        p ^= 1;
    }

    for (int reg = 0; reg < 4; ++reg)
        for (int off = 1; off < 16; off <<= 1) lsum[reg] += __shfl_xor(lsum[reg], off, 64);

    // v_rcp + mul (1 ulp on normalization; 16 divides -> 4 rcp + 16 mul)
    float rinv[4];
    for (int reg = 0; reg < 4; ++reg) rinv[reg] = __builtin_amdgcn_rcpf(lsum[reg]);

    for (int nt = 0; nt < 4; ++nt) {
        for (int reg = 0; reg < 4; ++reg) {
            int tt = t0 + wave * 16 + quad * 4 + reg;
            int d = nt * 16 + l16;
            Qb[((size_t)bh * 1024 + tt) * 64 + d] = f2bf_hw(acco[nt][reg] * rinv[reg]);
        }
    }
}

// ---------- 5. output projection (MFMA, bf16 Wo), dbuf + 2x2 wave retile ----------
__global__ __launch_bounds__(256) void out_proj(
    const unsigned short* __restrict__ AObf, const unsigned short* __restrict__ Wobf,
    const float* __restrict__ bo, float* __restrict__ out) {
    const int m0 = blockIdx.y * 64;
    const int n0 = blockIdx.x * 64;
    const int b = m0 >> 10, tt0 = m0 & 1023;
    __shared__ __align__(16) unsigned short As[2][64][72];
    __shared__ __align__(16) unsigned short Bs[2][64][72];
    int tid = threadIdx.x, wave = tid >> 6, lane = tid & 63, quad = lane >> 4, l16 = lane & 15;
    const int wr = (wave >> 1) * 32, wc = (wave & 1) * 32;
    int c0 = tid, c1 = tid + 256;
    int r0 = c0 >> 3, kc0 = (c0 & 7) << 3;
    int r1 = c1 >> 3, kc1 = (c1 & 7) << 3;

    // prefetch k0 = 0 (h = 0)
    uint4 ar0 = *(const uint4*)(AObf + (((size_t)(b * 8 + 0) * 1024 + tt0 + r0) << 6) + kc0);
    uint4 ar1 = *(const uint4*)(AObf + (((size_t)(b * 8 + 0) * 1024 + tt0 + r1) << 6) + kc1);
    uint4 br0 = *(const uint4*)(Wobf + (size_t)(n0 + r0) * 512 + kc0);
    uint4 br1 = *(const uint4*)(Wobf + (size_t)(n0 + r1) * 512 + kc1);

    f32x4 acc[2][2] = {};
    int p = 0;
    for (int k0 = 0; k0 < 512; k0 += 64) {
        *(uint4*)(&As[p][r0][kc0]) = ar0;
        *(uint4*)(&As[p][r1][kc1]) = ar1;
        *(uint4*)(&Bs[p][r0][kc0]) = br0;
        *(uint4*)(&Bs[p][r1][kc1]) = br1;
        int kn = k0 + 64;
        if (kn < 512) {
            int h = kn >> 6;
            ar0 = *(const uint4*)(AObf + (((size_t)(b * 8 + h) * 1024 + tt0 + r0) << 6) + kc0);
            ar1 = *(const uint4*)(AObf + (((size_t)(b * 8 + h) * 1024 + tt0 + r1) << 6) + kc1);
            br0 = *(const uint4*)(Wobf + (size_t)(n0 + r0) * 512 + kn + kc0);
            br1 = *(const uint4*)(Wobf + (size_t)(n0 + r1) * 512 + kn + kc1);
        }
        __syncthreads();   // buffer p staged; sole barrier this iteration
        for (int kk = 0; kk < 2; ++kk) {
            bf16x8 af0 = *(const bf16x8*)(&As[p][wr + l16][kk * 32 + quad * 8]);
            bf16x8 af1 = *(const bf16x8*)(&As[p][wr + 16 + l16][kk * 32 + quad * 8]);
            bf16x8 b0 = *(const bf16x8*)(&Bs[p][wc + l16][kk * 32 + quad * 8]);
            bf16x8 b1 = *(const bf16x8*)(&Bs[p][wc + 16 + l16][kk * 32 + quad * 8]);
            acc[0][0] = MFMA16(af0, b0, acc[0][0]);
            acc[0][1] = MFMA16(af0, b1, acc[0][1]);
            acc[1][0] = MFMA16(af1, b0, acc[1][0]);
            acc[1][1] = MFMA16(af1, b1, acc[1][1]);
        }
        p ^= 1;
    }
    for (int ni = 0; ni < 2; ++ni) {
        int col = n0 + wc + ni * 16 + l16;
        float bv_ = bo[col];
        for (int mi = 0; mi < 2; ++mi)
            for (int reg = 0; reg < 4; ++reg) {
                int row = m0 + wr + mi * 16 + quad * 4 + reg;
                out[(size_t)row * 512 + col] = acc[mi][ni][reg] + bv_;
            }
    }
}

extern "C" void kernel_launch(void* const* d_in, const int* in_sizes, int n_in,
                              void* d_out, int out_size, void* d_ws, size_t ws_size,
                              hipStream_t stream) {
    const void* x = nullptr; const void* Ws[4] = {}; const void* bs[4] = {};
    const void* relT = nullptr;
    int wi = 0, bi = 0, idx_x = -1;
    for (int i = 0; i < n_in; ++i) {
        long s = in_sizes[i];
        if ((s == 2097152 || s == 8388608) && !x) { x = d_in[i]; idx_x = i; }
        else if ((s == 262144 || s == 1048576) && wi < 4) Ws[wi++] = d_in[i];
        else if ((s == 512 || s == 2048) && bi < 4) bs[bi++] = d_in[i];
        else if ((s == 32832 || s == 131328) && !relT) relT = d_in[i];
    }
    const float *Wq, *Wk, *Wv, *Wo, *bq, *bk, *bv, *bo;
    if (x && wi == 4 && bi == 4 && relT) {
        bool sorted_order = (idx_x != 0);    // measured: dict order (idx_x==0)
        if (sorted_order) {
            Wq = (const float*)Ws[2]; Wk = (const float*)Ws[0];
            Wv = (const float*)Ws[3]; Wo = (const float*)Ws[1];
            bq = (const float*)bs[2]; bk = (const float*)bs[0];
            bv = (const float*)bs[3]; bo = (const float*)bs[1];
        } else {
            Wq = (const float*)Ws[0]; Wk = (const float*)Ws[1];
            Wv = (const float*)Ws[2]; Wo = (const float*)Ws[3];
            bq = (const float*)bs[0]; bk = (const float*)bs[1];
            bv = (const float*)bs[2]; bo = (const float*)bs[3];
        }
    } else {
        x = d_in[0];
        Wq = (const float*)d_in[2]; bq = (const float*)d_in[3];
        Wk = (const float*)d_in[4]; bk = (const float*)d_in[5];
        Wv = (const float*)d_in[6]; bv = (const float*)d_in[7];
        Wo = (const float*)d_in[8]; bo = (const float*)d_in[9];
        relT = d_in[10];
    }
    const float* xf  = (const float*)x;
    const float* rel = (const float*)relT;
    float* out = (float*)d_out;

    // ws: hdr 128K | Qb/Kb/VbT 3x4M | part 256K | pad 128K | Wbf 2M | xbf 4M
    char* ws = (char*)d_ws;
    float* Qsum = (float*)(ws + 8192);
    float* Rbuf = (float*)(ws + 16384);
    unsigned short* Qb  = (unsigned short*)(ws + 131072);
    unsigned short* Kb  = (unsigned short*)(ws + 131072 + (4 << 20));
    unsigned short* VbT = (unsigned short*)(ws + 131072 + (8 << 20));
    char* tail = ws + 131072 + (12 << 20);
    float* part = (float*)(tail);                        // 256 KB
    unsigned short* Wbf = (unsigned short*)(tail + 262144 + 131072);          // 2 MiB
    unsigned short* xbf = (unsigned short*)(tail + 262144 + 131072 + (2 << 20)); // 4 MiB

    prep_kernel<<<dim3(3200), dim3(256), 0, stream>>>(Wq, Wk, Wv, Wo, xf, Wbf, xbf, part);
    qkvq_fused<<<dim3(8, 128), dim3(256), 0, stream>>>(xbf, Wbf, bq, bk, bv, Qb, Kb, VbT,
                                                       part, Wq, Qsum);
    rbias_kernel<<<dim3(4104), dim3(256), 0, stream>>>(Qsum, rel, Rbuf);
    attn_kernel<<<dim3(512), dim3(256), 0, stream>>>(Qb, Kb, VbT, Rbuf);
    out_proj<<<dim3(8, 64), dim3(256), 0, stream>>>(Qb, Wbf + 3 * 262144, bo, out);
}